// Round 19
// baseline (162.785 us; speedup 1.0000x reference)
//
#include <hip/hip_runtime.h>
#include <stdint.h>

#define BB   2
#define SS   2048
#define DD   1024
#define HH   16
#define DKK  64
#define MM   (BB*SS)   // 4096 rows total

typedef __attribute__((ext_vector_type(4))) float f32x4;
typedef __attribute__((ext_vector_type(8))) short s16x8;

#define MFMA_B16(a, b, c) __builtin_amdgcn_mfma_f32_16x16x32_bf16((a), (b), (c), 0, 0, 0)

__device__ __forceinline__ ushort f2bf(float f) {
  uint u = __float_as_uint(f);
  u += 0x7FFFu + ((u >> 16) & 1u);   // round-to-nearest-even
  return (ushort)(u >> 16);
}
__device__ __forceinline__ float bf2f(ushort u) {
  return __uint_as_float((uint)u << 16);
}
// 2^x: __builtin_amdgcn_exp2f lowers to a bare v_exp_f32 (R17: 76->61us vs
// libm exp2f; R14's inline-asm broke TRANS hazards).  Scores pre-scaled log2(e).
#if __has_builtin(__builtin_amdgcn_exp2f)
#define EXP2(x) __builtin_amdgcn_exp2f(x)
#else
#define EXP2(x) exp2f(x)
#endif

// 8x fp32 (in regs) -> bf16 via packed cvt (RNE, proven R12)
__device__ __forceinline__ s16x8 pack8(float4 a, float4 b) {
  union { uint u[4]; s16x8 v; } r;
  asm("v_cvt_pk_bf16_f32 %0, %1, %2" : "=v"(r.u[0]) : "v"(a.x), "v"(a.y));
  asm("v_cvt_pk_bf16_f32 %0, %1, %2" : "=v"(r.u[1]) : "v"(a.z), "v"(a.w));
  asm("v_cvt_pk_bf16_f32 %0, %1, %2" : "=v"(r.u[2]) : "v"(b.x), "v"(b.y));
  asm("v_cvt_pk_bf16_f32 %0, %1, %2" : "=v"(r.u[3]) : "v"(b.z), "v"(b.w));
  return r.v;
}
__device__ __forceinline__ s16x8 cvt8(const float* src) {
  return pack8(*(const float4*)src, *(const float4*)(src + 4));
}

// Q pre-scale folds 1/sqrt(DK) AND log2(e).
#define QSCALE (0.125f * 1.4426950408889634f)

// ---------------- fp32 -> bf16 convert (8 elems/thread) — weights only ----------------
__global__ void cvt_kernel(const float* __restrict__ src, ushort* __restrict__ dst, int n) {
  int i = (blockIdx.x * 256 + threadIdx.x) * 8;
  if (i >= n) return;
  *(s16x8*)(dst + i) = cvt8(src + i);
}

// ---------------- fused Q/K/V projection: z selects proj ----------------
// R19: double-buffered LDS + T14 split (den-proven).  Per k-step: issue next
// step's fp32 A loads + bf16 W loads to REGISTERS at step top (HBM latency
// hides under the 16 MFMA), compute from buf[cur], pack+write regs into
// buf[cur^1], ONE barrier (was 2 barriers with cold fp32 loads serialized
// between them -> 64us latency-bound, R18 profile).
__global__ __launch_bounds__(256, 2) void qkv_proj(
    const float* __restrict__ Ia, const float* __restrict__ Ib, const float* __restrict__ Ic,
    const ushort* __restrict__ Wa, const ushort* __restrict__ Wb, const ushort* __restrict__ Wc,
    ushort* __restrict__ Oa, ushort* __restrict__ Ob, ushort* __restrict__ Oc)
{
  __shared__ ushort As[2][128 * 32];   // 16 KB
  __shared__ ushort Bs[2][128 * 32];   // 16 KB
  const int tid  = threadIdx.x;
  const int lane = tid & 63, wave = tid >> 6;
  const int q = lane & 15, g = lane >> 4;
  const int wr = wave >> 1, wc = wave & 1;
  const int mblk = blockIdx.x * 128, nblk = blockIdx.y * 128;
  const int mode = blockIdx.z;

  const float*  A = (mode == 0) ? Ia : (mode == 1) ? Ib : Ic;
  const ushort* W = (mode == 0) ? Wa : (mode == 1) ? Wb : Wc;

  f32x4 acc[4][4];
  {
    f32x4 z = {0.f, 0.f, 0.f, 0.f};
#pragma unroll
    for (int i = 0; i < 4; ++i)
#pragma unroll
      for (int j = 0; j < 4; ++j) acc[i][j] = z;
  }

  const int r0 = tid >> 2;            // staging row
  const int e0 = (tid & 3) * 8;       // staging element offset within row

  // prologue: stage k-step 0 into buf 0
#pragma unroll
  for (int it = 0; it < 2; ++it) {
    const int row = r0 + it * 64;
    *(s16x8*)&As[0][row * 32 + e0] = cvt8(A + (size_t)(mblk + row) * 1024 + e0);
    *(s16x8*)&Bs[0][row * 32 + e0] = *(const s16x8*)(W + (size_t)(nblk + row) * 1024 + e0);
  }
  __syncthreads();

  for (int s = 0; s < 32; ++s) {
    const int cur = s & 1;
    // T14: issue next step's loads to registers
    float4 fa[2][2];
    s16x8  wreg[2];
    if (s < 31) {
      const int k0 = (s + 1) * 32;
#pragma unroll
      for (int it = 0; it < 2; ++it) {
        const int row = r0 + it * 64;
        const float* pa = A + (size_t)(mblk + row) * 1024 + k0 + e0;
        fa[it][0] = *(const float4*)pa;
        fa[it][1] = *(const float4*)(pa + 4);
        wreg[it]  = *(const s16x8*)(W + (size_t)(nblk + row) * 1024 + k0 + e0);
      }
    }
    // compute from buf[cur]
    s16x8 af[4], bf[4];
#pragma unroll
    for (int t = 0; t < 4; ++t) {
      af[t] = *(const s16x8*)&As[cur][(wr * 64 + t * 16 + q) * 32 + g * 8];
      bf[t] = *(const s16x8*)&Bs[cur][(wc * 64 + t * 16 + q) * 32 + g * 8];
    }
#pragma unroll
    for (int mt = 0; mt < 4; ++mt)
#pragma unroll
      for (int nt = 0; nt < 4; ++nt)
        acc[mt][nt] = MFMA_B16(af[mt], bf[nt], acc[mt][nt]);
    // pack + write staged regs into the other buffer
    if (s < 31) {
#pragma unroll
      for (int it = 0; it < 2; ++it) {
        const int row = r0 + it * 64;
        *(s16x8*)&As[cur ^ 1][row * 32 + e0] = pack8(fa[it][0], fa[it][1]);
        *(s16x8*)&Bs[cur ^ 1][row * 32 + e0] = wreg[it];
      }
    }
    __syncthreads();
  }

  // epilogue (C layout: col = lane&15 (N), row = (lane>>4)*4 + j (M))
  if (mode == 2) {
    ushort* Vt = Oc;
#pragma unroll
    for (int mt = 0; mt < 4; ++mt)
#pragma unroll
      for (int nt = 0; nt < 4; ++nt) {
        const int s0 = mblk + wr * 64 + mt * 16 + g * 4;
        const int o  = nblk + wc * 64 + nt * 16 + q;
        const int h = o >> 6, dk = o & 63;
        const int b = s0 >> 11, sr = s0 & 2047;
        ushort4 pk;
        pk.x = f2bf(acc[mt][nt][0]); pk.y = f2bf(acc[mt][nt][1]);
        pk.z = f2bf(acc[mt][nt][2]); pk.w = f2bf(acc[mt][nt][3]);
        *(ushort4*)(Vt + ((size_t)((b * 16 + h) * 64 + dk)) * SS + sr) = pk;
      }
  } else {
    const float scale = (mode == 0) ? QSCALE : 1.0f;
    ushort* P = (mode == 0) ? Oa : Ob;
    ushort* wl = &As[0][wave * 1024];   // 2KB wave-private staging (reuse As)
    const int h0 = (nblk + wc * 64) >> 6;
#pragma unroll
    for (int mt = 0; mt < 4; ++mt) {
      const int s0 = mblk + wr * 64 + mt * 16;
      const int b  = s0 >> 11, sr0 = s0 & 2047;
#pragma unroll
      for (int nt = 0; nt < 4; ++nt)
#pragma unroll
        for (int j = 0; j < 4; ++j)
          wl[(g * 4 + j) * 64 + nt * 16 + q] = f2bf(acc[mt][nt][j] * scale);
      // same-wave LDS write->read: compiler inserts lgkmcnt wait
#pragma unroll
      for (int it = 0; it < 2; ++it) {
        s16x8 v = *(const s16x8*)((char*)wl + it * 1024 + lane * 16);
        const int lr = it * 8 + (lane >> 3);
        const int c  = (lane & 7) * 8;
        *(s16x8*)(P + ((size_t)((b * 16 + h0) * SS) + sr0 + lr) * DKK + c) = v;
      }
    }
  }
}

// ---------------- O-projection: Y = Ctx @ Wo^T -> fp32 d_out ----------------
__global__ __launch_bounds__(256, 2) void o_proj(
    const ushort* __restrict__ A, const ushort* __restrict__ W,
    float* __restrict__ O)
{
  __shared__ ushort As[128 * 32];
  __shared__ ushort Bs[128 * 32];
  const int tid  = threadIdx.x;
  const int lane = tid & 63, wave = tid >> 6;
  const int q = lane & 15, g = lane >> 4;
  const int wr = wave >> 1, wc = wave & 1;
  const int mblk = blockIdx.x * 128, nblk = blockIdx.y * 128;

  f32x4 acc[4][4];
  {
    f32x4 z = {0.f, 0.f, 0.f, 0.f};
#pragma unroll
    for (int i = 0; i < 4; ++i)
#pragma unroll
      for (int j = 0; j < 4; ++j) acc[i][j] = z;
  }

  const int r0 = tid >> 2;
  const int e0 = (tid & 3) * 8;
  for (int k0 = 0; k0 < 1024; k0 += 32) {
#pragma unroll
    for (int it = 0; it < 2; ++it) {
      const int row = r0 + it * 64;
      *(s16x8*)&As[row * 32 + e0] = *(const s16x8*)(A + (size_t)(mblk + row) * 1024 + k0 + e0);
      *(s16x8*)&Bs[row * 32 + e0] = *(const s16x8*)(W + (size_t)(nblk + row) * 1024 + k0 + e0);
    }
    __syncthreads();
    s16x8 af[4], bf[4];
#pragma unroll
    for (int t = 0; t < 4; ++t) {
      af[t] = *(const s16x8*)&As[(wr * 64 + t * 16 + q) * 32 + g * 8];
      bf[t] = *(const s16x8*)&Bs[(wc * 64 + t * 16 + q) * 32 + g * 8];
    }
#pragma unroll
    for (int mt = 0; mt < 4; ++mt)
#pragma unroll
      for (int nt = 0; nt < 4; ++nt)
        acc[mt][nt] = MFMA_B16(af[mt], bf[nt], acc[mt][nt]);
    __syncthreads();
  }

#pragma unroll
  for (int mt = 0; mt < 4; ++mt)
#pragma unroll
    for (int nt = 0; nt < 4; ++nt)
#pragma unroll
      for (int j = 0; j < 4; ++j) {
        const int s = mblk + wr * 64 + mt * 16 + g * 4 + j;
        const int o = nblk + wc * 64 + nt * 16 + q;
        O[(size_t)s * DD + o] = acc[mt][nt][j];
      }
}

// ---------------- pass 1: rden = 1/sum_h exp(s) — 64-wide steps, double-buffered ----------------
__global__ __launch_bounds__(256, 2) void den_kernel(
    const ushort* __restrict__ Qp, const ushort* __restrict__ Kp,
    ushort* __restrict__ Rden)
{
  __shared__ ushort smem[2][16384];     // [buf][As 8192 | Bs 8192] = 64 KB
  const int tid  = threadIdx.x;
  const int lane = tid & 63, wave = tid >> 6;
  const int q = lane & 15, g = lane >> 4;
  const int wr = wave >> 1, wc = wave & 1;
  const int kblk = blockIdx.x * 128, qblk = blockIdx.y * 128;
  const int b = blockIdx.z;

  f32x4 den[4][4];
  {
    f32x4 z = {0.f, 0.f, 0.f, 0.f};
#pragma unroll
    for (int i = 0; i < 4; ++i)
#pragma unroll
      for (int j = 0; j < 4; ++j) den[i][j] = z;
  }

  // staging: unit u = tid + i*256 (i 0..3): row = (tid>>3)+i*32, seg = tid&7
  const int srow = tid >> 3, sseg = tid & 7;
  const int sd   = (sseg * 8) ^ ((srow & 7) << 3);   // (row&7) invariant in i (i*32 % 8 == 0)

  const ushort* Kb0 = Kp + ((size_t)(b * 16) * SS + kblk) * DKK;
  const ushort* Qb0 = Qp + ((size_t)(b * 16) * SS + qblk) * DKK;

  // prologue: stage head 0 into buf 0
#pragma unroll
  for (int i = 0; i < 4; ++i) {
    const int row = srow + i * 32;
    *(s16x8*)&smem[0][row * 64 + sd]        = *(const s16x8*)(Kb0 + (size_t)row * DKK + sseg * 8);
    *(s16x8*)&smem[0][8192 + row * 64 + sd] = *(const s16x8*)(Qb0 + (size_t)row * DKK + sseg * 8);
  }
  __syncthreads();

  for (int s = 0; s < 16; ++s) {
    const int cur = s & 1;
    // T14: issue next head's loads
    s16x8 nA[4], nB[4];
    if (s < 15) {
      const ushort* Kh = Kb0 + (size_t)(s + 1) * SS * DKK;
      const ushort* Qh = Qb0 + (size_t)(s + 1) * SS * DKK;
#pragma unroll
      for (int i = 0; i < 4; ++i) {
        const int row = srow + i * 32;
        nA[i] = *(const s16x8*)(Kh + (size_t)row * DKK + sseg * 8);
        nB[i] = *(const s16x8*)(Qh + (size_t)row * DKK + sseg * 8);
      }
    }
    // compute head s from smem[cur]
    s16x8 af[4][2], bf[4][2];
#pragma unroll
    for (int t = 0; t < 4; ++t) {
      const int ra = wr * 64 + t * 16 + q;
      const int rb = wc * 64 + t * 16 + q;
      af[t][0] = *(const s16x8*)&smem[cur][ra * 64 + ((g * 8) ^ ((ra & 7) << 3))];
      af[t][1] = *(const s16x8*)&smem[cur][ra * 64 + ((32 + g * 8) ^ ((ra & 7) << 3))];
      bf[t][0] = *(const s16x8*)&smem[cur][8192 + rb * 64 + ((g * 8) ^ ((rb & 7) << 3))];
      bf[t][1] = *(const s16x8*)&smem[cur][8192 + rb * 64 + ((32 + g * 8) ^ ((rb & 7) << 3))];
    }
#pragma unroll
    for (int mt = 0; mt < 4; ++mt)
#pragma unroll
      for (int nt = 0; nt < 4; ++nt) {
        f32x4 c = {0.f, 0.f, 0.f, 0.f};
        c = MFMA_B16(af[mt][0], bf[nt][0], c);
        c = MFMA_B16(af[mt][1], bf[nt][1], c);
#pragma unroll
        for (int r = 0; r < 4; ++r)
          den[mt][nt][r] += EXP2(c[r]);
      }
    // write staged regs into the other buffer
    if (s < 15) {
#pragma unroll
      for (int i = 0; i < 4; ++i) {
        const int row = srow + i * 32;
        *(s16x8*)&smem[cur ^ 1][row * 64 + sd]        = nA[i];
        *(s16x8*)&smem[cur ^ 1][8192 + row * 64 + sd] = nB[i];
      }
    }
    __syncthreads();
  }

  // epilogue: transpose 64k x 64q wave tile -> rden[q][k] via swizzled LDS.
  char* aw2 = (char*)smem + wave * 8192;   // 8 KB wave-private (reuse smem)
#pragma unroll
  for (int mt = 0; mt < 4; ++mt)
#pragma unroll
    for (int nt = 0; nt < 4; ++nt) {
      const int ql = nt * 16 + q;           // q_local within wave tile
      const float i0 = 1.0f / den[mt][nt][0], i1 = 1.0f / den[mt][nt][1];
      const float i2 = 1.0f / den[mt][nt][2], i3 = 1.0f / den[mt][nt][3];
      uint2 pk;
      asm("v_cvt_pk_bf16_f32 %0, %1, %2" : "=v"(pk.x) : "v"(i0), "v"(i1));
      asm("v_cvt_pk_bf16_f32 %0, %1, %2" : "=v"(pk.y) : "v"(i2), "v"(i3));
      *(uint2*)(aw2 + ql * 128 + ((mt * 32 + g * 8) ^ ((ql & 7) << 4))) = pk;
    }
  // same-wave LDS write->read (lgkmcnt auto), then coalesced stores
#pragma unroll
  for (int it = 0; it < 8; ++it) {
    const int idx = it * 64 + lane;
    const int row = idx >> 3;               // q_local 0..63
    const int seg = idx & 7;                // 16B segment of k
    s16x8 v = *(const s16x8*)(aw2 + row * 128 + ((seg * 16) ^ ((row & 7) << 4)));
    *(s16x8*)(Rden + (size_t)b * SS * SS
              + (size_t)(qblk + wc * 64 + row) * SS
              + kblk + wr * 64 + seg * 8) = v;
  }
}

// ---------------- pass 2: block-tiled attention, double-buffered K/V ----------------
// R17 inner-loop form (R18's interleave+setprio regressed 61->63, reverted).
__global__ __launch_bounds__(512, 2) void attn5_kernel(
    const ushort* __restrict__ Qp, const ushort* __restrict__ Kp,
    const ushort* __restrict__ Vt, const ushort* __restrict__ Rden,
    ushort* __restrict__ Ctx)
{
  __shared__ ushort Ktile[2][64 * 64];   // 16 KB, row k (swz by k&7)
  __shared__ ushort Vtile[2][64 * 64];   // 16 KB, row dk (swz by dk&7)
  __shared__ ushort Rw_all[8][16 * 64];  // 16 KB, per-wave rden rows (swz)
  __shared__ ushort aw_all[8][16 * 64];  // 16 KB, per-wave P / epilogue

  const int tid  = threadIdx.x;
  const int lane = tid & 63;
  const int w    = tid >> 6;             // wave 0..7
  const int q    = lane & 15;
  const int g    = lane >> 4;
  const int bid  = blockIdx.x;
  const int bh   = bid & 31;
  const int b    = bh >> 4, h = bh & 15;
  const int qblk = (bid >> 5) * 128;

  const ushort* Qb = Qp + ((size_t)bh * SS + qblk + w * 16 + q) * DKK + g * 8;
  s16x8 qf0 = *(const s16x8*)(Qb);
  s16x8 qf1 = *(const s16x8*)(Qb + 32);

  const ushort* Ks = Kp + (size_t)bh * SS * DKK;
  const ushort* Vs = Vt + (size_t)bh * DKK * SS;
  const ushort* Rs = Rden + (size_t)b * SS * SS + (size_t)(qblk + w * 16) * SS;

  f32x4 acc[4];
  {
    f32x4 z = {0.f, 0.f, 0.f, 0.f};
#pragma unroll
    for (int n = 0; n < 4; ++n) acc[n] = z;
  }

  ushort* Rw = Rw_all[w];
  ushort* aw = aw_all[w];
  const int srow = tid >> 3, sseg = tid & 7;
  const int sd   = (sseg * 8) ^ ((srow & 7) << 3);
  const int r16  = lane >> 2;
  const int sgA  = (lane & 3) * 2;
  const int rd0  = r16 * 64 + ((sgA * 8) ^ ((r16 & 7) << 3));
  const int rd1  = r16 * 64 + (((sgA + 1) * 8) ^ ((r16 & 7) << 3));

  // prologue: stage phase 0 into buffer 0
  {
    s16x8 gK  = *(const s16x8*)(Ks + tid * 8);
    s16x8 gV  = *(const s16x8*)(Vs + (size_t)srow * SS + sseg * 8);
    s16x8 gR0 = *(const s16x8*)(Rs + (size_t)r16 * SS + sgA * 8);
    s16x8 gR1 = *(const s16x8*)(Rs + (size_t)r16 * SS + (sgA + 1) * 8);
    *(s16x8*)&Ktile[0][srow * 64 + sd] = gK;
    *(s16x8*)&Vtile[0][srow * 64 + sd] = gV;
    *(s16x8*)&Rw[rd0] = gR0;
    *(s16x8*)&Rw[rd1] = gR1;
  }
  __syncthreads();

  for (int kt = 0; kt < 32; ++kt) {
    const int cur = kt & 1;
    // ---- issue next tile's global loads (latency hides under compute)
    s16x8 gK, gV, gR0, gR1;
    if (kt < 31) {
      const int k1 = (kt + 1) * 64;
      gK  = *(const s16x8*)(Ks + (size_t)k1 * DKK + tid * 8);
      gV  = *(const s16x8*)(Vs + (size_t)srow * SS + k1 + sseg * 8);
      gR0 = *(const s16x8*)(Rs + (size_t)r16 * SS + k1 + sgA * 8);
      gR1 = *(const s16x8*)(Rs + (size_t)r16 * SS + k1 + (sgA + 1) * 8);
    }
    const ushort* Kt = Ktile[cur];
    const ushort* Vv = Vtile[cur];

    // ---- QK scores -> exp2 * rden -> P into wave-private aw
#pragma unroll
    for (int ks = 0; ks < 4; ++ks) {
      const int kr = ks * 16 + q;
      s16x8 a0 = *(const s16x8*)&Kt[kr * 64 + ((g * 8) ^ ((kr & 7) << 3))];
      s16x8 a1 = *(const s16x8*)&Kt[kr * 64 + ((32 + g * 8) ^ ((kr & 7) << 3))];
      f32x4 c = {0.f, 0.f, 0.f, 0.f};
      c = MFMA_B16(a0, qf0, c);
      c = MFMA_B16(a1, qf1, c);
      ushort4 rv = *(const ushort4*)&Rw[q * 64 + (((ks * 2 + (g >> 1)) ^ (q & 7)) * 8) + (g & 1) * 4];
      float p0 = EXP2(c[0]) * bf2f(rv.x);
      float p1 = EXP2(c[1]) * bf2f(rv.y);
      float p2 = EXP2(c[2]) * bf2f(rv.z);
      float p3 = EXP2(c[3]) * bf2f(rv.w);
      uint2 pp;
      asm("v_cvt_pk_bf16_f32 %0, %1, %2" : "=v"(pp.x) : "v"(p0), "v"(p1));
      asm("v_cvt_pk_bf16_f32 %0, %1, %2" : "=v"(pp.y) : "v"(p2), "v"(p3));
      *(uint2*)&aw[q * 64 + ((ks * 16 + g * 4) ^ ((q & 7) << 3))] = pp;
    }
    // ---- PV over the 64-key tile (same-wave aw; lgkmcnt auto)
#pragma unroll
    for (int kc = 0; kc < 2; ++kc) {
      s16x8 vf[4];
#pragma unroll
      for (int n = 0; n < 4; ++n) {
        const int vr = n * 16 + q;
        vf[n] = *(const s16x8*)&Vv[vr * 64 + ((kc * 32 + g * 8) ^ ((vr & 7) << 3))];
      }
      s16x8 pa = *(const s16x8*)&aw[q * 64 + ((kc * 32 + g * 8) ^ ((q & 7) << 3))];
#pragma unroll
      for (int n = 0; n < 4; ++n)
        acc[n] = MFMA_B16(pa, vf[n], acc[n]);
    }
    // ---- write staged regs into the other buffer (R: wave-private, in-order)
    if (kt < 31) {
      *(s16x8*)&Ktile[cur ^ 1][srow * 64 + sd] = gK;
      *(s16x8*)&Vtile[cur ^ 1][srow * 64 + sd] = gV;
      *(s16x8*)&Rw[rd0] = gR0;
      *(s16x8*)&Rw[rd1] = gR1;
    }
    __syncthreads();
  }

  // epilogue: stage 16 rows x 64 cols in wave-private aw, then coalesced
  // 16B/lane stores (each instr: 8 rows x 128B contiguous).
#pragma unroll
  for (int n = 0; n < 4; ++n)
#pragma unroll
    for (int j = 0; j < 4; ++j)
      aw[(g * 4 + j) * 64 + n * 16 + q] = f2bf(acc[n][j]);
  ushort* P = Ctx + ((size_t)(b * SS) + qblk + w * 16) * DD + h * 64;
#pragma unroll
  for (int it = 0; it < 2; ++it) {
    const int idx = it * 64 + lane;
    const int row = idx >> 3;
    const int seg = idx & 7;
    s16x8 v = *(const s16x8*)&aw[row * 64 + seg * 8];
    *(s16x8*)(P + (size_t)row * DD + seg * 8) = v;
  }
}

extern "C" void kernel_launch(void* const* d_in, const int* in_sizes, int n_in,
                              void* d_out, int out_size, void* d_ws, size_t ws_size,
                              hipStream_t stream) {
  const float* Query = (const float*)d_in[0];
  const float* Key   = (const float*)d_in[1];
  const float* Value = (const float*)d_in[2];
  const float* Wq    = (const float*)d_in[3];
  const float* Wk    = (const float*)d_in[4];
  const float* Wv    = (const float*)d_in[5];
  const float* Wo    = (const float*)d_in[6];

  size_t off = 0;
  char* ws = (char*)d_ws;
  auto alloc = [&](size_t bytes) -> void* {
    void* p = ws + off;
    off += (bytes + 255) & ~(size_t)255;
    return p;
  };
  const size_t nX = (size_t)MM * DD;       // 4194304
  const size_t nW = (size_t)DD * DD;       // 1048576
  const size_t nS = (size_t)BB * SS * SS;  // 8388608
  ushort* Wqb  = (ushort*)alloc(nW * 2);
  ushort* Wkb  = (ushort*)alloc(nW * 2);
  ushort* Wvb  = (ushort*)alloc(nW * 2);
  ushort* Wob  = (ushort*)alloc(nW * 2);
  ushort* Qp   = (ushort*)alloc(nX * 2);
  ushort* Kp   = (ushort*)alloc(nX * 2);
  ushort* Vtb  = (ushort*)alloc(nX * 2);
  ushort* Rden = (ushort*)alloc(nS * 2);   // bf16 1/den, 16.7 MB
  ushort* Ctx  = (ushort*)alloc(nX * 2);

  // weights -> bf16 (16 MB fp32 total, streaming)
  cvt_kernel<<<(int)(nW / 2048), 256, 0, stream>>>(Wq, Wqb, (int)nW);
  cvt_kernel<<<(int)(nW / 2048), 256, 0, stream>>>(Wk, Wkb, (int)nW);
  cvt_kernel<<<(int)(nW / 2048), 256, 0, stream>>>(Wv, Wvb, (int)nW);
  cvt_kernel<<<(int)(nW / 2048), 256, 0, stream>>>(Wo, Wob, (int)nW);

  // fused Q/K/V projections: 768 blocks = 3 blocks/CU
  qkv_proj<<<dim3(32, 8, 3), 256, 0, stream>>>(
      Query, Key, Value, Wqb, Wkb, Wvb, Qp, Kp, Vtb);

  den_kernel<<<dim3(16, 16, 2), 256, 0, stream>>>(Qp, Kp, Rden);
  attn5_kernel<<<512, 512, 0, stream>>>(Qp, Kp, Vtb, Rden, Ctx);

  o_proj<<<dim3(32, 8), 256, 0, stream>>>(Ctx, Wob, (float*)d_out);
}

// Round 20
// 154.833 us; speedup vs baseline: 1.0514x; 1.0514x over previous
//
#include <hip/hip_runtime.h>
#include <stdint.h>

#define BB   2
#define SS   2048
#define DD   1024
#define HH   16
#define DKK  64
#define MM   (BB*SS)   // 4096 rows total

typedef __attribute__((ext_vector_type(4))) float f32x4;
typedef __attribute__((ext_vector_type(8))) short s16x8;

#define MFMA_B16(a, b, c) __builtin_amdgcn_mfma_f32_16x16x32_bf16((a), (b), (c), 0, 0, 0)

__device__ __forceinline__ ushort f2bf(float f) {
  uint u = __float_as_uint(f);
  u += 0x7FFFu + ((u >> 16) & 1u);   // round-to-nearest-even
  return (ushort)(u >> 16);
}
__device__ __forceinline__ float bf2f(ushort u) {
  return __uint_as_float((uint)u << 16);
}
// 2^x: __builtin_amdgcn_exp2f lowers to a bare v_exp_f32 (R17: 76->61us vs
// libm exp2f; R14's inline-asm broke TRANS hazards).  Scores pre-scaled log2(e).
#if __has_builtin(__builtin_amdgcn_exp2f)
#define EXP2(x) __builtin_amdgcn_exp2f(x)
#else
#define EXP2(x) exp2f(x)
#endif

// 8x fp32 (in regs) -> bf16 via packed cvt (RNE, proven R12)
__device__ __forceinline__ s16x8 pack8(float4 a, float4 b) {
  union { uint u[4]; s16x8 v; } r;
  asm("v_cvt_pk_bf16_f32 %0, %1, %2" : "=v"(r.u[0]) : "v"(a.x), "v"(a.y));
  asm("v_cvt_pk_bf16_f32 %0, %1, %2" : "=v"(r.u[1]) : "v"(a.z), "v"(a.w));
  asm("v_cvt_pk_bf16_f32 %0, %1, %2" : "=v"(r.u[2]) : "v"(b.x), "v"(b.y));
  asm("v_cvt_pk_bf16_f32 %0, %1, %2" : "=v"(r.u[3]) : "v"(b.z), "v"(b.w));
  return r.v;
}
__device__ __forceinline__ s16x8 cvt8(const float* src) {
  return pack8(*(const float4*)src, *(const float4*)(src + 4));
}

// Q pre-scale folds 1/sqrt(DK) AND log2(e).
#define QSCALE (0.125f * 1.4426950408889634f)

// ---------------- fp32 -> bf16 convert (8 elems/thread) — weights only ----------------
__global__ void cvt_kernel(const float* __restrict__ src, ushort* __restrict__ dst, int n) {
  int i = (blockIdx.x * 256 + threadIdx.x) * 8;
  if (i >= n) return;
  *(s16x8*)(dst + i) = cvt8(src + i);
}

// ---------------- fused Q/K/V projection: z selects proj ----------------
// R20: distance-2 pipeline.  Loads for step s+2 issue at step s (regs), get
// LDS-written at end of step s+1, consumed at s+2 -> each cold fp32 HBM load
// has a full step (+barrier) of latency cover (R19's same-step write gave only
// the ~300cy MFMA window vs ~900cy HBM latency -> no gain).  Loads issue
// before a __syncthreads and are used after -> compiler cannot sink them.
__global__ __launch_bounds__(256, 2) void qkv_proj(
    const float* __restrict__ Ia, const float* __restrict__ Ib, const float* __restrict__ Ic,
    const ushort* __restrict__ Wa, const ushort* __restrict__ Wb, const ushort* __restrict__ Wc,
    ushort* __restrict__ Oa, ushort* __restrict__ Ob, ushort* __restrict__ Oc)
{
  __shared__ ushort As[2][128 * 32];   // 16 KB
  __shared__ ushort Bs[2][128 * 32];   // 16 KB
  const int tid  = threadIdx.x;
  const int lane = tid & 63, wave = tid >> 6;
  const int q = lane & 15, g = lane >> 4;
  const int wr = wave >> 1, wc = wave & 1;
  const int mblk = blockIdx.x * 128, nblk = blockIdx.y * 128;
  const int mode = blockIdx.z;

  const float*  A = (mode == 0) ? Ia : (mode == 1) ? Ib : Ic;
  const ushort* W = (mode == 0) ? Wa : (mode == 1) ? Wb : Wc;

  f32x4 acc[4][4];
  {
    f32x4 z = {0.f, 0.f, 0.f, 0.f};
#pragma unroll
    for (int i = 0; i < 4; ++i)
#pragma unroll
      for (int j = 0; j < 4; ++j) acc[i][j] = z;
  }

  const int r0 = tid >> 2;            // staging row
  const int e0 = (tid & 3) * 8;       // staging element offset within row
  const size_t arow0 = (size_t)(mblk + r0) * 1024 + e0;
  const size_t arow1 = (size_t)(mblk + r0 + 64) * 1024 + e0;
  const size_t wrow0 = (size_t)(nblk + r0) * 1024 + e0;
  const size_t wrow1 = (size_t)(nblk + r0 + 64) * 1024 + e0;

  // prologue: stage step 0 direct; load step 1 into regs
#pragma unroll
  for (int it = 0; it < 2; ++it) {
    const int row = r0 + it * 64;
    *(s16x8*)&As[0][row * 32 + e0] = cvt8(A + (it ? arow1 : arow0));
    *(s16x8*)&Bs[0][row * 32 + e0] = *(const s16x8*)(W + (it ? wrow1 : wrow0));
  }
  float4 fa0_0, fa0_1, fa1_0, fa1_1;
  s16x8  wg0, wg1;
  {
    const float* p0 = A + arow0 + 32;
    const float* p1 = A + arow1 + 32;
    fa0_0 = *(const float4*)p0;  fa0_1 = *(const float4*)(p0 + 4);
    fa1_0 = *(const float4*)p1;  fa1_1 = *(const float4*)(p1 + 4);
    wg0 = *(const s16x8*)(W + wrow0 + 32);
    wg1 = *(const s16x8*)(W + wrow1 + 32);
  }
  __syncthreads();

  for (int s = 0; s < 32; ++s) {
    const int cur = s & 1;
    // issue step s+2 loads
    float4 na0_0, na0_1, na1_0, na1_1;
    s16x8  nw0, nw1;
    if (s < 30) {
      const int k0 = (s + 2) * 32;
      const float* p0 = A + arow0 + k0;
      const float* p1 = A + arow1 + k0;
      na0_0 = *(const float4*)p0;  na0_1 = *(const float4*)(p0 + 4);
      na1_0 = *(const float4*)p1;  na1_1 = *(const float4*)(p1 + 4);
      nw0 = *(const s16x8*)(W + wrow0 + k0);
      nw1 = *(const s16x8*)(W + wrow1 + k0);
    }
    // compute step s from buf[cur]
    s16x8 af[4], bf[4];
#pragma unroll
    for (int t = 0; t < 4; ++t) {
      af[t] = *(const s16x8*)&As[cur][(wr * 64 + t * 16 + q) * 32 + g * 8];
      bf[t] = *(const s16x8*)&Bs[cur][(wc * 64 + t * 16 + q) * 32 + g * 8];
    }
#pragma unroll
    for (int mt = 0; mt < 4; ++mt)
#pragma unroll
      for (int nt = 0; nt < 4; ++nt)
        acc[mt][nt] = MFMA_B16(af[mt], bf[nt], acc[mt][nt]);
    // write step s+1 regs into the other buffer
    if (s < 31) {
      *(s16x8*)&As[cur ^ 1][r0 * 32 + e0]        = pack8(fa0_0, fa0_1);
      *(s16x8*)&As[cur ^ 1][(r0 + 64) * 32 + e0] = pack8(fa1_0, fa1_1);
      *(s16x8*)&Bs[cur ^ 1][r0 * 32 + e0]        = wg0;
      *(s16x8*)&Bs[cur ^ 1][(r0 + 64) * 32 + e0] = wg1;
    }
    // rotate
    if (s < 30) {
      fa0_0 = na0_0; fa0_1 = na0_1; fa1_0 = na1_0; fa1_1 = na1_1;
      wg0 = nw0; wg1 = nw1;
    }
    __syncthreads();
  }

  // epilogue (C layout: col = lane&15 (N), row = (lane>>4)*4 + j (M))
  if (mode == 2) {
    ushort* Vt = Oc;
#pragma unroll
    for (int mt = 0; mt < 4; ++mt)
#pragma unroll
      for (int nt = 0; nt < 4; ++nt) {
        const int s0 = mblk + wr * 64 + mt * 16 + g * 4;
        const int o  = nblk + wc * 64 + nt * 16 + q;
        const int h = o >> 6, dk = o & 63;
        const int b = s0 >> 11, sr = s0 & 2047;
        ushort4 pk;
        pk.x = f2bf(acc[mt][nt][0]); pk.y = f2bf(acc[mt][nt][1]);
        pk.z = f2bf(acc[mt][nt][2]); pk.w = f2bf(acc[mt][nt][3]);
        *(ushort4*)(Vt + ((size_t)((b * 16 + h) * 64 + dk)) * SS + sr) = pk;
      }
  } else {
    const float scale = (mode == 0) ? QSCALE : 1.0f;
    ushort* P = (mode == 0) ? Oa : Ob;
    ushort* wl = &As[0][wave * 1024];   // 2KB wave-private staging (reuse As)
    const int h0 = (nblk + wc * 64) >> 6;
#pragma unroll
    for (int mt = 0; mt < 4; ++mt) {
      const int s0 = mblk + wr * 64 + mt * 16;
      const int b  = s0 >> 11, sr0 = s0 & 2047;
#pragma unroll
      for (int nt = 0; nt < 4; ++nt)
#pragma unroll
        for (int j = 0; j < 4; ++j)
          wl[(g * 4 + j) * 64 + nt * 16 + q] = f2bf(acc[mt][nt][j] * scale);
      // same-wave LDS write->read: compiler inserts lgkmcnt wait
#pragma unroll
      for (int it = 0; it < 2; ++it) {
        s16x8 v = *(const s16x8*)((char*)wl + it * 1024 + lane * 16);
        const int lr = it * 8 + (lane >> 3);
        const int c  = (lane & 7) * 8;
        *(s16x8*)(P + ((size_t)((b * 16 + h0) * SS) + sr0 + lr) * DKK + c) = v;
      }
    }
  }
}

// ---------------- O-projection: Y = Ctx @ Wo^T -> fp32 d_out ----------------
// R20: same distance-2 double-buffered pipeline (den-proven transform).
__global__ __launch_bounds__(256, 2) void o_proj(
    const ushort* __restrict__ A, const ushort* __restrict__ W,
    float* __restrict__ O)
{
  __shared__ ushort As[2][128 * 32];
  __shared__ ushort Bs[2][128 * 32];
  const int tid  = threadIdx.x;
  const int lane = tid & 63, wave = tid >> 6;
  const int q = lane & 15, g = lane >> 4;
  const int wr = wave >> 1, wc = wave & 1;
  const int mblk = blockIdx.x * 128, nblk = blockIdx.y * 128;

  f32x4 acc[4][4];
  {
    f32x4 z = {0.f, 0.f, 0.f, 0.f};
#pragma unroll
    for (int i = 0; i < 4; ++i)
#pragma unroll
      for (int j = 0; j < 4; ++j) acc[i][j] = z;
  }

  const int r0 = tid >> 2;
  const int e0 = (tid & 3) * 8;
  const size_t arow0 = (size_t)(mblk + r0) * 1024 + e0;
  const size_t arow1 = (size_t)(mblk + r0 + 64) * 1024 + e0;
  const size_t wrow0 = (size_t)(nblk + r0) * 1024 + e0;
  const size_t wrow1 = (size_t)(nblk + r0 + 64) * 1024 + e0;

  // prologue: stage step 0 direct; load step 1 into regs
#pragma unroll
  for (int it = 0; it < 2; ++it) {
    const int row = r0 + it * 64;
    *(s16x8*)&As[0][row * 32 + e0] = *(const s16x8*)(A + (it ? arow1 : arow0));
    *(s16x8*)&Bs[0][row * 32 + e0] = *(const s16x8*)(W + (it ? wrow1 : wrow0));
  }
  s16x8 ag0, ag1, wg0, wg1;
  {
    ag0 = *(const s16x8*)(A + arow0 + 32);
    ag1 = *(const s16x8*)(A + arow1 + 32);
    wg0 = *(const s16x8*)(W + wrow0 + 32);
    wg1 = *(const s16x8*)(W + wrow1 + 32);
  }
  __syncthreads();

  for (int s = 0; s < 32; ++s) {
    const int cur = s & 1;
    s16x8 na0, na1, nw0, nw1;
    if (s < 30) {
      const int k0 = (s + 2) * 32;
      na0 = *(const s16x8*)(A + arow0 + k0);
      na1 = *(const s16x8*)(A + arow1 + k0);
      nw0 = *(const s16x8*)(W + wrow0 + k0);
      nw1 = *(const s16x8*)(W + wrow1 + k0);
    }
    s16x8 af[4], bf[4];
#pragma unroll
    for (int t = 0; t < 4; ++t) {
      af[t] = *(const s16x8*)&As[cur][(wr * 64 + t * 16 + q) * 32 + g * 8];
      bf[t] = *(const s16x8*)&Bs[cur][(wc * 64 + t * 16 + q) * 32 + g * 8];
    }
#pragma unroll
    for (int mt = 0; mt < 4; ++mt)
#pragma unroll
      for (int nt = 0; nt < 4; ++nt)
        acc[mt][nt] = MFMA_B16(af[mt], bf[nt], acc[mt][nt]);
    if (s < 31) {
      *(s16x8*)&As[cur ^ 1][r0 * 32 + e0]        = ag0;
      *(s16x8*)&As[cur ^ 1][(r0 + 64) * 32 + e0] = ag1;
      *(s16x8*)&Bs[cur ^ 1][r0 * 32 + e0]        = wg0;
      *(s16x8*)&Bs[cur ^ 1][(r0 + 64) * 32 + e0] = wg1;
    }
    if (s < 30) { ag0 = na0; ag1 = na1; wg0 = nw0; wg1 = nw1; }
    __syncthreads();
  }

#pragma unroll
  for (int mt = 0; mt < 4; ++mt)
#pragma unroll
    for (int nt = 0; nt < 4; ++nt)
#pragma unroll
      for (int j = 0; j < 4; ++j) {
        const int s = mblk + wr * 64 + mt * 16 + g * 4 + j;
        const int o = nblk + wc * 64 + nt * 16 + q;
        O[(size_t)s * DD + o] = acc[mt][nt][j];
      }
}

// ---------------- pass 1: rden = 1/sum_h exp(s) — 64-wide steps, double-buffered ----------------
__global__ __launch_bounds__(256, 2) void den_kernel(
    const ushort* __restrict__ Qp, const ushort* __restrict__ Kp,
    ushort* __restrict__ Rden)
{
  __shared__ ushort smem[2][16384];     // [buf][As 8192 | Bs 8192] = 64 KB
  const int tid  = threadIdx.x;
  const int lane = tid & 63, wave = tid >> 6;
  const int q = lane & 15, g = lane >> 4;
  const int wr = wave >> 1, wc = wave & 1;
  const int kblk = blockIdx.x * 128, qblk = blockIdx.y * 128;
  const int b = blockIdx.z;

  f32x4 den[4][4];
  {
    f32x4 z = {0.f, 0.f, 0.f, 0.f};
#pragma unroll
    for (int i = 0; i < 4; ++i)
#pragma unroll
      for (int j = 0; j < 4; ++j) den[i][j] = z;
  }

  const int srow = tid >> 3, sseg = tid & 7;
  const int sd   = (sseg * 8) ^ ((srow & 7) << 3);

  const ushort* Kb0 = Kp + ((size_t)(b * 16) * SS + kblk) * DKK;
  const ushort* Qb0 = Qp + ((size_t)(b * 16) * SS + qblk) * DKK;

  // prologue: stage head 0 into buf 0
#pragma unroll
  for (int i = 0; i < 4; ++i) {
    const int row = srow + i * 32;
    *(s16x8*)&smem[0][row * 64 + sd]        = *(const s16x8*)(Kb0 + (size_t)row * DKK + sseg * 8);
    *(s16x8*)&smem[0][8192 + row * 64 + sd] = *(const s16x8*)(Qb0 + (size_t)row * DKK + sseg * 8);
  }
  __syncthreads();

  for (int s = 0; s < 16; ++s) {
    const int cur = s & 1;
    s16x8 nA[4], nB[4];
    if (s < 15) {
      const ushort* Kh = Kb0 + (size_t)(s + 1) * SS * DKK;
      const ushort* Qh = Qb0 + (size_t)(s + 1) * SS * DKK;
#pragma unroll
      for (int i = 0; i < 4; ++i) {
        const int row = srow + i * 32;
        nA[i] = *(const s16x8*)(Kh + (size_t)row * DKK + sseg * 8);
        nB[i] = *(const s16x8*)(Qh + (size_t)row * DKK + sseg * 8);
      }
    }
    s16x8 af[4][2], bf[4][2];
#pragma unroll
    for (int t = 0; t < 4; ++t) {
      const int ra = wr * 64 + t * 16 + q;
      const int rb = wc * 64 + t * 16 + q;
      af[t][0] = *(const s16x8*)&smem[cur][ra * 64 + ((g * 8) ^ ((ra & 7) << 3))];
      af[t][1] = *(const s16x8*)&smem[cur][ra * 64 + ((32 + g * 8) ^ ((ra & 7) << 3))];
      bf[t][0] = *(const s16x8*)&smem[cur][8192 + rb * 64 + ((g * 8) ^ ((rb & 7) << 3))];
      bf[t][1] = *(const s16x8*)&smem[cur][8192 + rb * 64 + ((32 + g * 8) ^ ((rb & 7) << 3))];
    }
#pragma unroll
    for (int mt = 0; mt < 4; ++mt)
#pragma unroll
      for (int nt = 0; nt < 4; ++nt) {
        f32x4 c = {0.f, 0.f, 0.f, 0.f};
        c = MFMA_B16(af[mt][0], bf[nt][0], c);
        c = MFMA_B16(af[mt][1], bf[nt][1], c);
#pragma unroll
        for (int r = 0; r < 4; ++r)
          den[mt][nt][r] += EXP2(c[r]);
      }
    if (s < 15) {
#pragma unroll
      for (int i = 0; i < 4; ++i) {
        const int row = srow + i * 32;
        *(s16x8*)&smem[cur ^ 1][row * 64 + sd]        = nA[i];
        *(s16x8*)&smem[cur ^ 1][8192 + row * 64 + sd] = nB[i];
      }
    }
    __syncthreads();
  }

  // epilogue: transpose 64k x 64q wave tile -> rden[q][k] via swizzled LDS.
  char* aw2 = (char*)smem + wave * 8192;   // 8 KB wave-private (reuse smem)
#pragma unroll
  for (int mt = 0; mt < 4; ++mt)
#pragma unroll
    for (int nt = 0; nt < 4; ++nt) {
      const int ql = nt * 16 + q;           // q_local within wave tile
      const float i0 = 1.0f / den[mt][nt][0], i1 = 1.0f / den[mt][nt][1];
      const float i2 = 1.0f / den[mt][nt][2], i3 = 1.0f / den[mt][nt][3];
      uint2 pk;
      asm("v_cvt_pk_bf16_f32 %0, %1, %2" : "=v"(pk.x) : "v"(i0), "v"(i1));
      asm("v_cvt_pk_bf16_f32 %0, %1, %2" : "=v"(pk.y) : "v"(i2), "v"(i3));
      *(uint2*)(aw2 + ql * 128 + ((mt * 32 + g * 8) ^ ((ql & 7) << 4))) = pk;
    }
  // same-wave LDS write->read (lgkmcnt auto), then coalesced stores
#pragma unroll
  for (int it = 0; it < 8; ++it) {
    const int idx = it * 64 + lane;
    const int row = idx >> 3;               // q_local 0..63
    const int seg = idx & 7;                // 16B segment of k
    s16x8 v = *(const s16x8*)(aw2 + row * 128 + ((seg * 16) ^ ((row & 7) << 4)));
    *(s16x8*)(Rden + (size_t)b * SS * SS
              + (size_t)(qblk + wc * 64 + row) * SS
              + kblk + wr * 64 + seg * 8) = v;
  }
}

// ---------------- pass 2: block-tiled attention, double-buffered K/V ----------------
// R17 inner-loop form (R18's interleave+setprio regressed 61->63, reverted).
__global__ __launch_bounds__(512, 2) void attn5_kernel(
    const ushort* __restrict__ Qp, const ushort* __restrict__ Kp,
    const ushort* __restrict__ Vt, const ushort* __restrict__ Rden,
    ushort* __restrict__ Ctx)
{
  __shared__ ushort Ktile[2][64 * 64];   // 16 KB, row k (swz by k&7)
  __shared__ ushort Vtile[2][64 * 64];   // 16 KB, row dk (swz by dk&7)
  __shared__ ushort Rw_all[8][16 * 64];  // 16 KB, per-wave rden rows (swz)
  __shared__ ushort aw_all[8][16 * 64];  // 16 KB, per-wave P / epilogue

  const int tid  = threadIdx.x;
  const int lane = tid & 63;
  const int w    = tid >> 6;             // wave 0..7
  const int q    = lane & 15;
  const int g    = lane >> 4;
  const int bid  = blockIdx.x;
  const int bh   = bid & 31;
  const int b    = bh >> 4, h = bh & 15;
  const int qblk = (bid >> 5) * 128;

  const ushort* Qb = Qp + ((size_t)bh * SS + qblk + w * 16 + q) * DKK + g * 8;
  s16x8 qf0 = *(const s16x8*)(Qb);
  s16x8 qf1 = *(const s16x8*)(Qb + 32);

  const ushort* Ks = Kp + (size_t)bh * SS * DKK;
  const ushort* Vs = Vt + (size_t)bh * DKK * SS;
  const ushort* Rs = Rden + (size_t)b * SS * SS + (size_t)(qblk + w * 16) * SS;

  f32x4 acc[4];
  {
    f32x4 z = {0.f, 0.f, 0.f, 0.f};
#pragma unroll
    for (int n = 0; n < 4; ++n) acc[n] = z;
  }

  ushort* Rw = Rw_all[w];
  ushort* aw = aw_all[w];
  const int srow = tid >> 3, sseg = tid & 7;
  const int sd   = (sseg * 8) ^ ((srow & 7) << 3);
  const int r16  = lane >> 2;
  const int sgA  = (lane & 3) * 2;
  const int rd0  = r16 * 64 + ((sgA * 8) ^ ((r16 & 7) << 3));
  const int rd1  = r16 * 64 + (((sgA + 1) * 8) ^ ((r16 & 7) << 3));

  // prologue: stage phase 0 into buffer 0
  {
    s16x8 gK  = *(const s16x8*)(Ks + tid * 8);
    s16x8 gV  = *(const s16x8*)(Vs + (size_t)srow * SS + sseg * 8);
    s16x8 gR0 = *(const s16x8*)(Rs + (size_t)r16 * SS + sgA * 8);
    s16x8 gR1 = *(const s16x8*)(Rs + (size_t)r16 * SS + (sgA + 1) * 8);
    *(s16x8*)&Ktile[0][srow * 64 + sd] = gK;
    *(s16x8*)&Vtile[0][srow * 64 + sd] = gV;
    *(s16x8*)&Rw[rd0] = gR0;
    *(s16x8*)&Rw[rd1] = gR1;
  }
  __syncthreads();

  for (int kt = 0; kt < 32; ++kt) {
    const int cur = kt & 1;
    // ---- issue next tile's global loads (latency hides under compute)
    s16x8 gK, gV, gR0, gR1;
    if (kt < 31) {
      const int k1 = (kt + 1) * 64;
      gK  = *(const s16x8*)(Ks + (size_t)k1 * DKK + tid * 8);
      gV  = *(const s16x8*)(Vs + (size_t)srow * SS + k1 + sseg * 8);
      gR0 = *(const s16x8*)(Rs + (size_t)r16 * SS + k1 + sgA * 8);
      gR1 = *(const s16x8*)(Rs + (size_t)r16 * SS + k1 + (sgA + 1) * 8);
    }
    const ushort* Kt = Ktile[cur];
    const ushort* Vv = Vtile[cur];

    // ---- QK scores -> exp2 * rden -> P into wave-private aw
#pragma unroll
    for (int ks = 0; ks < 4; ++ks) {
      const int kr = ks * 16 + q;
      s16x8 a0 = *(const s16x8*)&Kt[kr * 64 + ((g * 8) ^ ((kr & 7) << 3))];
      s16x8 a1 = *(const s16x8*)&Kt[kr * 64 + ((32 + g * 8) ^ ((kr & 7) << 3))];
      f32x4 c = {0.f, 0.f, 0.f, 0.f};
      c = MFMA_B16(a0, qf0, c);
      c = MFMA_B16(a1, qf1, c);
      ushort4 rv = *(const ushort4*)&Rw[q * 64 + (((ks * 2 + (g >> 1)) ^ (q & 7)) * 8) + (g & 1) * 4];
      float p0 = EXP2(c[0]) * bf2f(rv.x);
      float p1 = EXP2(c[1]) * bf2f(rv.y);
      float p2 = EXP2(c[2]) * bf2f(rv.z);
      float p3 = EXP2(c[3]) * bf2f(rv.w);
      uint2 pp;
      asm("v_cvt_pk_bf16_f32 %0, %1, %2" : "=v"(pp.x) : "v"(p0), "v"(p1));
      asm("v_cvt_pk_bf16_f32 %0, %1, %2" : "=v"(pp.y) : "v"(p2), "v"(p3));
      *(uint2*)&aw[q * 64 + ((ks * 16 + g * 4) ^ ((q & 7) << 3))] = pp;
    }
    // ---- PV over the 64-key tile (same-wave aw; lgkmcnt auto)
#pragma unroll
    for (int kc = 0; kc < 2; ++kc) {
      s16x8 vf[4];
#pragma unroll
      for (int n = 0; n < 4; ++n) {
        const int vr = n * 16 + q;
        vf[n] = *(const s16x8*)&Vv[vr * 64 + ((kc * 32 + g * 8) ^ ((vr & 7) << 3))];
      }
      s16x8 pa = *(const s16x8*)&aw[q * 64 + ((kc * 32 + g * 8) ^ ((q & 7) << 3))];
#pragma unroll
      for (int n = 0; n < 4; ++n)
        acc[n] = MFMA_B16(pa, vf[n], acc[n]);
    }
    // ---- write staged regs into the other buffer (R: wave-private, in-order)
    if (kt < 31) {
      *(s16x8*)&Ktile[cur ^ 1][srow * 64 + sd] = gK;
      *(s16x8*)&Vtile[cur ^ 1][srow * 64 + sd] = gV;
      *(s16x8*)&Rw[rd0] = gR0;
      *(s16x8*)&Rw[rd1] = gR1;
    }
    __syncthreads();
  }

  // epilogue: stage 16 rows x 64 cols in wave-private aw, then coalesced
  // 16B/lane stores (each instr: 8 rows x 128B contiguous).
#pragma unroll
  for (int n = 0; n < 4; ++n)
#pragma unroll
    for (int j = 0; j < 4; ++j)
      aw[(g * 4 + j) * 64 + n * 16 + q] = f2bf(acc[n][j]);
  ushort* P = Ctx + ((size_t)(b * SS) + qblk + w * 16) * DD + h * 64;
#pragma unroll
  for (int it = 0; it < 2; ++it) {
    const int idx = it * 64 + lane;
    const int row = idx >> 3;
    const int seg = idx & 7;
    s16x8 v = *(const s16x8*)&aw[row * 64 + seg * 8];
    *(s16x8*)(P + (size_t)row * DD + seg * 8) = v;
  }
}

extern "C" void kernel_launch(void* const* d_in, const int* in_sizes, int n_in,
                              void* d_out, int out_size, void* d_ws, size_t ws_size,
                              hipStream_t stream) {
  const float* Query = (const float*)d_in[0];
  const float* Key   = (const float*)d_in[1];
  const float* Value = (const float*)d_in[2];
  const float* Wq    = (const float*)d_in[3];
  const float* Wk    = (const float*)d_in[4];
  const float* Wv    = (const float*)d_in[5];
  const float* Wo    = (const float*)d_in[6];

  size_t off = 0;
  char* ws = (char*)d_ws;
  auto alloc = [&](size_t bytes) -> void* {
    void* p = ws + off;
    off += (bytes + 255) & ~(size_t)255;
    return p;
  };
  const size_t nX = (size_t)MM * DD;       // 4194304
  const size_t nW = (size_t)DD * DD;       // 1048576
  const size_t nS = (size_t)BB * SS * SS;  // 8388608
  ushort* Wqb  = (ushort*)alloc(nW * 2);
  ushort* Wkb  = (ushort*)alloc(nW * 2);
  ushort* Wvb  = (ushort*)alloc(nW * 2);
  ushort* Wob  = (ushort*)alloc(nW * 2);
  ushort* Qp   = (ushort*)alloc(nX * 2);
  ushort* Kp   = (ushort*)alloc(nX * 2);
  ushort* Vtb  = (ushort*)alloc(nX * 2);
  ushort* Rden = (ushort*)alloc(nS * 2);   // bf16 1/den, 16.7 MB
  ushort* Ctx  = (ushort*)alloc(nX * 2);

  // weights -> bf16 (16 MB fp32 total, streaming)
  cvt_kernel<<<(int)(nW / 2048), 256, 0, stream>>>(Wq, Wqb, (int)nW);
  cvt_kernel<<<(int)(nW / 2048), 256, 0, stream>>>(Wk, Wkb, (int)nW);
  cvt_kernel<<<(int)(nW / 2048), 256, 0, stream>>>(Wv, Wvb, (int)nW);
  cvt_kernel<<<(int)(nW / 2048), 256, 0, stream>>>(Wo, Wob, (int)nW);

  // fused Q/K/V projections: 768 blocks = 3 blocks/CU
  qkv_proj<<<dim3(32, 8, 3), 256, 0, stream>>>(
      Query, Key, Value, Wqb, Wkb, Wvb, Qp, Kp, Vtb);

  den_kernel<<<dim3(16, 16, 2), 256, 0, stream>>>(Qp, Kp, Rden);
  attn5_kernel<<<512, 512, 0, stream>>>(Qp, Kp, Vtb, Rden, Ctx);

  o_proj<<<dim3(32, 8), 256, 0, stream>>>(Ctx, Wob, (float*)d_out);
}

// Round 22
// 147.627 us; speedup vs baseline: 1.1027x; 1.0488x over previous
//
#include <hip/hip_runtime.h>
#include <stdint.h>

#define BB   2
#define SS   2048
#define DD   1024
#define HH   16
#define DKK  64
#define MM   (BB*SS)   // 4096 rows total

typedef __attribute__((ext_vector_type(4))) float f32x4;
typedef __attribute__((ext_vector_type(8))) short s16x8;

#define MFMA_B16(a, b, c) __builtin_amdgcn_mfma_f32_16x16x32_bf16((a), (b), (c), 0, 0, 0)

__device__ __forceinline__ ushort f2bf(float f) {
  uint u = __float_as_uint(f);
  u += 0x7FFFu + ((u >> 16) & 1u);   // round-to-nearest-even
  return (ushort)(u >> 16);
}
__device__ __forceinline__ float bf2f(ushort u) {
  return __uint_as_float((uint)u << 16);
}
// 2^x: __builtin_amdgcn_exp2f lowers to a bare v_exp_f32 (R17: 76->61us vs
// libm exp2f; R14's inline-asm broke TRANS hazards).  Scores pre-scaled log2(e).
#if __has_builtin(__builtin_amdgcn_exp2f)
#define EXP2(x) __builtin_amdgcn_exp2f(x)
#else
#define EXP2(x) exp2f(x)
#endif

// 8x fp32 (in regs) -> bf16 via packed cvt (RNE, proven R12)
__device__ __forceinline__ s16x8 pack8(float4 a, float4 b) {
  union { uint u[4]; s16x8 v; } r;
  asm("v_cvt_pk_bf16_f32 %0, %1, %2" : "=v"(r.u[0]) : "v"(a.x), "v"(a.y));
  asm("v_cvt_pk_bf16_f32 %0, %1, %2" : "=v"(r.u[1]) : "v"(a.z), "v"(a.w));
  asm("v_cvt_pk_bf16_f32 %0, %1, %2" : "=v"(r.u[2]) : "v"(b.x), "v"(b.y));
  asm("v_cvt_pk_bf16_f32 %0, %1, %2" : "=v"(r.u[3]) : "v"(b.z), "v"(b.w));
  return r.v;
}
__device__ __forceinline__ s16x8 cvt8(const float* src) {
  return pack8(*(const float4*)src, *(const float4*)(src + 4));
}

// Q pre-scale folds 1/sqrt(DK) AND log2(e).
#define QSCALE (0.125f * 1.4426950408889634f)

// ---------------- fp32 -> bf16 convert: all 4 weights in ONE launch ----------------
__global__ void cvt4_kernel(const float* __restrict__ s0, const float* __restrict__ s1,
                            const float* __restrict__ s2, const float* __restrict__ s3,
                            ushort* __restrict__ d0, ushort* __restrict__ d1,
                            ushort* __restrict__ d2, ushort* __restrict__ d3, int n) {
  const int w = blockIdx.y;
  const float*  src = (w == 0) ? s0 : (w == 1) ? s1 : (w == 2) ? s2 : s3;
  ushort*       dst = (w == 0) ? d0 : (w == 1) ? d1 : (w == 2) ? d2 : d3;
  int i = (blockIdx.x * 256 + threadIdx.x) * 8;
  if (i >= n) return;
  *(s16x8*)(dst + i) = cvt8(src + i);
}

// ---------------- fused Q/K/V projection: z selects proj ----------------
// R20: distance-2 pipeline (loads for step s+2 issue at step s; full step of
// HBM latency cover; proven 162.8->154.8us).
__global__ __launch_bounds__(256, 2) void qkv_proj(
    const float* __restrict__ Ia, const float* __restrict__ Ib, const float* __restrict__ Ic,
    const ushort* __restrict__ Wa, const ushort* __restrict__ Wb, const ushort* __restrict__ Wc,
    ushort* __restrict__ Oa, ushort* __restrict__ Ob, ushort* __restrict__ Oc)
{
  __shared__ ushort As[2][128 * 32];   // 16 KB
  __shared__ ushort Bs[2][128 * 32];   // 16 KB
  const int tid  = threadIdx.x;
  const int lane = tid & 63, wave = tid >> 6;
  const int q = lane & 15, g = lane >> 4;
  const int wr = wave >> 1, wc = wave & 1;
  const int mblk = blockIdx.x * 128, nblk = blockIdx.y * 128;
  const int mode = blockIdx.z;

  const float*  A = (mode == 0) ? Ia : (mode == 1) ? Ib : Ic;
  const ushort* W = (mode == 0) ? Wa : (mode == 1) ? Wb : Wc;

  f32x4 acc[4][4];
  {
    f32x4 z = {0.f, 0.f, 0.f, 0.f};
#pragma unroll
    for (int i = 0; i < 4; ++i)
#pragma unroll
      for (int j = 0; j < 4; ++j) acc[i][j] = z;
  }

  const int r0 = tid >> 2;            // staging row
  const int e0 = (tid & 3) * 8;       // staging element offset within row
  const size_t arow0 = (size_t)(mblk + r0) * 1024 + e0;
  const size_t arow1 = (size_t)(mblk + r0 + 64) * 1024 + e0;
  const size_t wrow0 = (size_t)(nblk + r0) * 1024 + e0;
  const size_t wrow1 = (size_t)(nblk + r0 + 64) * 1024 + e0;

  // prologue: stage step 0 direct; load step 1 into regs
#pragma unroll
  for (int it = 0; it < 2; ++it) {
    const int row = r0 + it * 64;
    *(s16x8*)&As[0][row * 32 + e0] = cvt8(A + (it ? arow1 : arow0));
    *(s16x8*)&Bs[0][row * 32 + e0] = *(const s16x8*)(W + (it ? wrow1 : wrow0));
  }
  float4 fa0_0, fa0_1, fa1_0, fa1_1;
  s16x8  wg0, wg1;
  {
    const float* p0 = A + arow0 + 32;
    const float* p1 = A + arow1 + 32;
    fa0_0 = *(const float4*)p0;  fa0_1 = *(const float4*)(p0 + 4);
    fa1_0 = *(const float4*)p1;  fa1_1 = *(const float4*)(p1 + 4);
    wg0 = *(const s16x8*)(W + wrow0 + 32);
    wg1 = *(const s16x8*)(W + wrow1 + 32);
  }
  __syncthreads();

  for (int s = 0; s < 32; ++s) {
    const int cur = s & 1;
    // issue step s+2 loads
    float4 na0_0, na0_1, na1_0, na1_1;
    s16x8  nw0, nw1;
    if (s < 30) {
      const int k0 = (s + 2) * 32;
      const float* p0 = A + arow0 + k0;
      const float* p1 = A + arow1 + k0;
      na0_0 = *(const float4*)p0;  na0_1 = *(const float4*)(p0 + 4);
      na1_0 = *(const float4*)p1;  na1_1 = *(const float4*)(p1 + 4);
      nw0 = *(const s16x8*)(W + wrow0 + k0);
      nw1 = *(const s16x8*)(W + wrow1 + k0);
    }
    // compute step s from buf[cur]
    s16x8 af[4], bf[4];
#pragma unroll
    for (int t = 0; t < 4; ++t) {
      af[t] = *(const s16x8*)&As[cur][(wr * 64 + t * 16 + q) * 32 + g * 8];
      bf[t] = *(const s16x8*)&Bs[cur][(wc * 64 + t * 16 + q) * 32 + g * 8];
    }
#pragma unroll
    for (int mt = 0; mt < 4; ++mt)
#pragma unroll
      for (int nt = 0; nt < 4; ++nt)
        acc[mt][nt] = MFMA_B16(af[mt], bf[nt], acc[mt][nt]);
    // write step s+1 regs into the other buffer
    if (s < 31) {
      *(s16x8*)&As[cur ^ 1][r0 * 32 + e0]        = pack8(fa0_0, fa0_1);
      *(s16x8*)&As[cur ^ 1][(r0 + 64) * 32 + e0] = pack8(fa1_0, fa1_1);
      *(s16x8*)&Bs[cur ^ 1][r0 * 32 + e0]        = wg0;
      *(s16x8*)&Bs[cur ^ 1][(r0 + 64) * 32 + e0] = wg1;
    }
    // rotate
    if (s < 30) {
      fa0_0 = na0_0; fa0_1 = na0_1; fa1_0 = na1_0; fa1_1 = na1_1;
      wg0 = nw0; wg1 = nw1;
    }
    __syncthreads();
  }

  // epilogue (C layout: col = lane&15 (N), row = (lane>>4)*4 + j (M))
  if (mode == 2) {
    ushort* Vt = Oc;
#pragma unroll
    for (int mt = 0; mt < 4; ++mt)
#pragma unroll
      for (int nt = 0; nt < 4; ++nt) {
        const int s0 = mblk + wr * 64 + mt * 16 + g * 4;
        const int o  = nblk + wc * 64 + nt * 16 + q;
        const int h = o >> 6, dk = o & 63;
        const int b = s0 >> 11, sr = s0 & 2047;
        ushort4 pk;
        pk.x = f2bf(acc[mt][nt][0]); pk.y = f2bf(acc[mt][nt][1]);
        pk.z = f2bf(acc[mt][nt][2]); pk.w = f2bf(acc[mt][nt][3]);
        *(ushort4*)(Vt + ((size_t)((b * 16 + h) * 64 + dk)) * SS + sr) = pk;
      }
  } else {
    const float scale = (mode == 0) ? QSCALE : 1.0f;
    ushort* P = (mode == 0) ? Oa : Ob;
    ushort* wl = &As[0][wave * 1024];   // 2KB wave-private staging (reuse As)
    const int h0 = (nblk + wc * 64) >> 6;
#pragma unroll
    for (int mt = 0; mt < 4; ++mt) {
      const int s0 = mblk + wr * 64 + mt * 16;
      const int b  = s0 >> 11, sr0 = s0 & 2047;
#pragma unroll
      for (int nt = 0; nt < 4; ++nt)
#pragma unroll
        for (int j = 0; j < 4; ++j)
          wl[(g * 4 + j) * 64 + nt * 16 + q] = f2bf(acc[mt][nt][j] * scale);
      // same-wave LDS write->read: compiler inserts lgkmcnt wait
#pragma unroll
      for (int it = 0; it < 2; ++it) {
        s16x8 v = *(const s16x8*)((char*)wl + it * 1024 + lane * 16);
        const int lr = it * 8 + (lane >> 3);
        const int c  = (lane & 7) * 8;
        *(s16x8*)(P + ((size_t)((b * 16 + h0) * SS) + sr0 + lr) * DKK + c) = v;
      }
    }
  }
}

// ---------------- O-projection: Y = Ctx @ Wo^T -> fp32 d_out ----------------
__global__ __launch_bounds__(256, 2) void o_proj(
    const ushort* __restrict__ A, const ushort* __restrict__ W,
    float* __restrict__ O)
{
  __shared__ ushort As[2][128 * 32];
  __shared__ ushort Bs[2][128 * 32];
  const int tid  = threadIdx.x;
  const int lane = tid & 63, wave = tid >> 6;
  const int q = lane & 15, g = lane >> 4;
  const int wr = wave >> 1, wc = wave & 1;
  const int mblk = blockIdx.x * 128, nblk = blockIdx.y * 128;

  f32x4 acc[4][4];
  {
    f32x4 z = {0.f, 0.f, 0.f, 0.f};
#pragma unroll
    for (int i = 0; i < 4; ++i)
#pragma unroll
      for (int j = 0; j < 4; ++j) acc[i][j] = z;
  }

  const int r0 = tid >> 2;
  const int e0 = (tid & 3) * 8;
  const size_t arow0 = (size_t)(mblk + r0) * 1024 + e0;
  const size_t arow1 = (size_t)(mblk + r0 + 64) * 1024 + e0;
  const size_t wrow0 = (size_t)(nblk + r0) * 1024 + e0;
  const size_t wrow1 = (size_t)(nblk + r0 + 64) * 1024 + e0;

  // prologue: stage step 0 direct; load step 1 into regs
#pragma unroll
  for (int it = 0; it < 2; ++it) {
    const int row = r0 + it * 64;
    *(s16x8*)&As[0][row * 32 + e0] = *(const s16x8*)(A + (it ? arow1 : arow0));
    *(s16x8*)&Bs[0][row * 32 + e0] = *(const s16x8*)(W + (it ? wrow1 : wrow0));
  }
  s16x8 ag0, ag1, wg0, wg1;
  {
    ag0 = *(const s16x8*)(A + arow0 + 32);
    ag1 = *(const s16x8*)(A + arow1 + 32);
    wg0 = *(const s16x8*)(W + wrow0 + 32);
    wg1 = *(const s16x8*)(W + wrow1 + 32);
  }
  __syncthreads();

  for (int s = 0; s < 32; ++s) {
    const int cur = s & 1;
    s16x8 na0, na1, nw0, nw1;
    if (s < 30) {
      const int k0 = (s + 2) * 32;
      na0 = *(const s16x8*)(A + arow0 + k0);
      na1 = *(const s16x8*)(A + arow1 + k0);
      nw0 = *(const s16x8*)(W + wrow0 + k0);
      nw1 = *(const s16x8*)(W + wrow1 + k0);
    }
    s16x8 af[4], bf[4];
#pragma unroll
    for (int t = 0; t < 4; ++t) {
      af[t] = *(const s16x8*)&As[cur][(wr * 64 + t * 16 + q) * 32 + g * 8];
      bf[t] = *(const s16x8*)&Bs[cur][(wc * 64 + t * 16 + q) * 32 + g * 8];
    }
#pragma unroll
    for (int mt = 0; mt < 4; ++mt)
#pragma unroll
      for (int nt = 0; nt < 4; ++nt)
        acc[mt][nt] = MFMA_B16(af[mt], bf[nt], acc[mt][nt]);
    if (s < 31) {
      *(s16x8*)&As[cur ^ 1][r0 * 32 + e0]        = ag0;
      *(s16x8*)&As[cur ^ 1][(r0 + 64) * 32 + e0] = ag1;
      *(s16x8*)&Bs[cur ^ 1][r0 * 32 + e0]        = wg0;
      *(s16x8*)&Bs[cur ^ 1][(r0 + 64) * 32 + e0] = wg1;
    }
    if (s < 30) { ag0 = na0; ag1 = na1; wg0 = nw0; wg1 = nw1; }
    __syncthreads();
  }

#pragma unroll
  for (int mt = 0; mt < 4; ++mt)
#pragma unroll
    for (int nt = 0; nt < 4; ++nt)
#pragma unroll
      for (int j = 0; j < 4; ++j) {
        const int s = mblk + wr * 64 + mt * 16 + g * 4 + j;
        const int o = nblk + wc * 64 + nt * 16 + q;
        O[(size_t)s * DD + o] = acc[mt][nt][j];
      }
}

// ---------------- pass 1: rden = 1/sum_h exp(s) — 64-wide steps, double-buffered ----------------
__global__ __launch_bounds__(256, 2) void den_kernel(
    const ushort* __restrict__ Qp, const ushort* __restrict__ Kp,
    ushort* __restrict__ Rden)
{
  __shared__ ushort smem[2][16384];     // [buf][As 8192 | Bs 8192] = 64 KB
  const int tid  = threadIdx.x;
  const int lane = tid & 63, wave = tid >> 6;
  const int q = lane & 15, g = lane >> 4;
  const int wr = wave >> 1, wc = wave & 1;
  const int kblk = blockIdx.x * 128, qblk = blockIdx.y * 128;
  const int b = blockIdx.z;

  f32x4 den[4][4];
  {
    f32x4 z = {0.f, 0.f, 0.f, 0.f};
#pragma unroll
    for (int i = 0; i < 4; ++i)
#pragma unroll
      for (int j = 0; j < 4; ++j) den[i][j] = z;
  }

  const int srow = tid >> 3, sseg = tid & 7;
  const int sd   = (sseg * 8) ^ ((srow & 7) << 3);

  const ushort* Kb0 = Kp + ((size_t)(b * 16) * SS + kblk) * DKK;
  const ushort* Qb0 = Qp + ((size_t)(b * 16) * SS + qblk) * DKK;

  // prologue: stage head 0 into buf 0
#pragma unroll
  for (int i = 0; i < 4; ++i) {
    const int row = srow + i * 32;
    *(s16x8*)&smem[0][row * 64 + sd]        = *(const s16x8*)(Kb0 + (size_t)row * DKK + sseg * 8);
    *(s16x8*)&smem[0][8192 + row * 64 + sd] = *(const s16x8*)(Qb0 + (size_t)row * DKK + sseg * 8);
  }
  __syncthreads();

  for (int s = 0; s < 16; ++s) {
    const int cur = s & 1;
    s16x8 nA[4], nB[4];
    if (s < 15) {
      const ushort* Kh = Kb0 + (size_t)(s + 1) * SS * DKK;
      const ushort* Qh = Qb0 + (size_t)(s + 1) * SS * DKK;
#pragma unroll
      for (int i = 0; i < 4; ++i) {
        const int row = srow + i * 32;
        nA[i] = *(const s16x8*)(Kh + (size_t)row * DKK + sseg * 8);
        nB[i] = *(const s16x8*)(Qh + (size_t)row * DKK + sseg * 8);
      }
    }
    s16x8 af[4][2], bf[4][2];
#pragma unroll
    for (int t = 0; t < 4; ++t) {
      const int ra = wr * 64 + t * 16 + q;
      const int rb = wc * 64 + t * 16 + q;
      af[t][0] = *(const s16x8*)&smem[cur][ra * 64 + ((g * 8) ^ ((ra & 7) << 3))];
      af[t][1] = *(const s16x8*)&smem[cur][ra * 64 + ((32 + g * 8) ^ ((ra & 7) << 3))];
      bf[t][0] = *(const s16x8*)&smem[cur][8192 + rb * 64 + ((g * 8) ^ ((rb & 7) << 3))];
      bf[t][1] = *(const s16x8*)&smem[cur][8192 + rb * 64 + ((32 + g * 8) ^ ((rb & 7) << 3))];
    }
#pragma unroll
    for (int mt = 0; mt < 4; ++mt)
#pragma unroll
      for (int nt = 0; nt < 4; ++nt) {
        f32x4 c = {0.f, 0.f, 0.f, 0.f};
        c = MFMA_B16(af[mt][0], bf[nt][0], c);
        c = MFMA_B16(af[mt][1], bf[nt][1], c);
#pragma unroll
        for (int r = 0; r < 4; ++r)
          den[mt][nt][r] += EXP2(c[r]);
      }
    if (s < 15) {
#pragma unroll
      for (int i = 0; i < 4; ++i) {
        const int row = srow + i * 32;
        *(s16x8*)&smem[cur ^ 1][row * 64 + sd]        = nA[i];
        *(s16x8*)&smem[cur ^ 1][8192 + row * 64 + sd] = nB[i];
      }
    }
    __syncthreads();
  }

  // epilogue: transpose 64k x 64q wave tile -> rden[q][k] via swizzled LDS.
  char* aw2 = (char*)smem + wave * 8192;   // 8 KB wave-private (reuse smem)
#pragma unroll
  for (int mt = 0; mt < 4; ++mt)
#pragma unroll
    for (int nt = 0; nt < 4; ++nt) {
      const int ql = nt * 16 + q;           // q_local within wave tile
      const float i0 = 1.0f / den[mt][nt][0], i1 = 1.0f / den[mt][nt][1];
      const float i2 = 1.0f / den[mt][nt][2], i3 = 1.0f / den[mt][nt][3];
      uint2 pk;
      asm("v_cvt_pk_bf16_f32 %0, %1, %2" : "=v"(pk.x) : "v"(i0), "v"(i1));
      asm("v_cvt_pk_bf16_f32 %0, %1, %2" : "=v"(pk.y) : "v"(i2), "v"(i3));
      *(uint2*)(aw2 + ql * 128 + ((mt * 32 + g * 8) ^ ((ql & 7) << 4))) = pk;
    }
  // same-wave LDS write->read (lgkmcnt auto), then coalesced stores
#pragma unroll
  for (int it = 0; it < 8; ++it) {
    const int idx = it * 64 + lane;
    const int row = idx >> 3;               // q_local 0..63
    const int seg = idx & 7;                // 16B segment of k
    s16x8 v = *(const s16x8*)(aw2 + row * 128 + ((seg * 16) ^ ((row & 7) << 4)));
    *(s16x8*)(Rden + (size_t)b * SS * SS
              + (size_t)(qblk + wc * 64 + row) * SS
              + kblk + wr * 64 + seg * 8) = v;
  }
}

// ---------------- pass 2: block-tiled attention, double-buffered K/V ----------------
// R20 form exactly (R21's ds_bpermute re-layout had a pull-vs-push selection
// bug — source lane's selector, not dest's — and the corrected version costs
// more DS ops than the LDS bounce it replaces; abandoned).
__global__ __launch_bounds__(512, 2) void attn5_kernel(
    const ushort* __restrict__ Qp, const ushort* __restrict__ Kp,
    const ushort* __restrict__ Vt, const ushort* __restrict__ Rden,
    ushort* __restrict__ Ctx)
{
  __shared__ ushort Ktile[2][64 * 64];   // 16 KB, row k (swz by k&7)
  __shared__ ushort Vtile[2][64 * 64];   // 16 KB, row dk (swz by dk&7)
  __shared__ ushort Rw_all[8][16 * 64];  // 16 KB, per-wave rden rows (swz)
  __shared__ ushort aw_all[8][16 * 64];  // 16 KB, per-wave P / epilogue

  const int tid  = threadIdx.x;
  const int lane = tid & 63;
  const int w    = tid >> 6;             // wave 0..7
  const int q    = lane & 15;
  const int g    = lane >> 4;
  const int bid  = blockIdx.x;
  const int bh   = bid & 31;
  const int b    = bh >> 4, h = bh & 15;
  const int qblk = (bid >> 5) * 128;

  const ushort* Qb = Qp + ((size_t)bh * SS + qblk + w * 16 + q) * DKK + g * 8;
  s16x8 qf0 = *(const s16x8*)(Qb);
  s16x8 qf1 = *(const s16x8*)(Qb + 32);

  const ushort* Ks = Kp + (size_t)bh * SS * DKK;
  const ushort* Vs = Vt + (size_t)bh * DKK * SS;
  const ushort* Rs = Rden + (size_t)b * SS * SS + (size_t)(qblk + w * 16) * SS;

  f32x4 acc[4];
  {
    f32x4 z = {0.f, 0.f, 0.f, 0.f};
#pragma unroll
    for (int n = 0; n < 4; ++n) acc[n] = z;
  }

  ushort* Rw = Rw_all[w];
  ushort* aw = aw_all[w];
  const int srow = tid >> 3, sseg = tid & 7;
  const int sd   = (sseg * 8) ^ ((srow & 7) << 3);
  const int r16  = lane >> 2;
  const int sgA  = (lane & 3) * 2;
  const int rd0  = r16 * 64 + ((sgA * 8) ^ ((r16 & 7) << 3));
  const int rd1  = r16 * 64 + (((sgA + 1) * 8) ^ ((r16 & 7) << 3));

  // prologue: stage phase 0 into buffer 0
  {
    s16x8 gK  = *(const s16x8*)(Ks + tid * 8);
    s16x8 gV  = *(const s16x8*)(Vs + (size_t)srow * SS + sseg * 8);
    s16x8 gR0 = *(const s16x8*)(Rs + (size_t)r16 * SS + sgA * 8);
    s16x8 gR1 = *(const s16x8*)(Rs + (size_t)r16 * SS + (sgA + 1) * 8);
    *(s16x8*)&Ktile[0][srow * 64 + sd] = gK;
    *(s16x8*)&Vtile[0][srow * 64 + sd] = gV;
    *(s16x8*)&Rw[rd0] = gR0;
    *(s16x8*)&Rw[rd1] = gR1;
  }
  __syncthreads();

  for (int kt = 0; kt < 32; ++kt) {
    const int cur = kt & 1;
    // ---- issue next tile's global loads (latency hides under compute)
    s16x8 gK, gV, gR0, gR1;
    if (kt < 31) {
      const int k1 = (kt + 1) * 64;
      gK  = *(const s16x8*)(Ks + (size_t)k1 * DKK + tid * 8);
      gV  = *(const s16x8*)(Vs + (size_t)srow * SS + k1 + sseg * 8);
      gR0 = *(const s16x8*)(Rs + (size_t)r16 * SS + k1 + sgA * 8);
      gR1 = *(const s16x8*)(Rs + (size_t)r16 * SS + k1 + (sgA + 1) * 8);
    }
    const ushort* Kt = Ktile[cur];
    const ushort* Vv = Vtile[cur];

    // ---- QK scores -> exp2 * rden -> P into wave-private aw
#pragma unroll
    for (int ks = 0; ks < 4; ++ks) {
      const int kr = ks * 16 + q;
      s16x8 a0 = *(const s16x8*)&Kt[kr * 64 + ((g * 8) ^ ((kr & 7) << 3))];
      s16x8 a1 = *(const s16x8*)&Kt[kr * 64 + ((32 + g * 8) ^ ((kr & 7) << 3))];
      f32x4 c = {0.f, 0.f, 0.f, 0.f};
      c = MFMA_B16(a0, qf0, c);
      c = MFMA_B16(a1, qf1, c);
      ushort4 rv = *(const ushort4*)&Rw[q * 64 + (((ks * 2 + (g >> 1)) ^ (q & 7)) * 8) + (g & 1) * 4];
      float p0 = EXP2(c[0]) * bf2f(rv.x);
      float p1 = EXP2(c[1]) * bf2f(rv.y);
      float p2 = EXP2(c[2]) * bf2f(rv.z);
      float p3 = EXP2(c[3]) * bf2f(rv.w);
      uint2 pp;
      asm("v_cvt_pk_bf16_f32 %0, %1, %2" : "=v"(pp.x) : "v"(p0), "v"(p1));
      asm("v_cvt_pk_bf16_f32 %0, %1, %2" : "=v"(pp.y) : "v"(p2), "v"(p3));
      *(uint2*)&aw[q * 64 + ((ks * 16 + g * 4) ^ ((q & 7) << 3))] = pp;
    }
    // ---- PV over the 64-key tile (same-wave aw; lgkmcnt auto)
#pragma unroll
    for (int kc = 0; kc < 2; ++kc) {
      s16x8 vf[4];
#pragma unroll
      for (int n = 0; n < 4; ++n) {
        const int vr = n * 16 + q;
        vf[n] = *(const s16x8*)&Vv[vr * 64 + ((kc * 32 + g * 8) ^ ((vr & 7) << 3))];
      }
      s16x8 pa = *(const s16x8*)&aw[q * 64 + ((kc * 32 + g * 8) ^ ((q & 7) << 3))];
#pragma unroll
      for (int n = 0; n < 4; ++n)
        acc[n] = MFMA_B16(pa, vf[n], acc[n]);
    }
    // ---- write staged regs into the other buffer (R: wave-private, in-order)
    if (kt < 31) {
      *(s16x8*)&Ktile[cur ^ 1][srow * 64 + sd] = gK;
      *(s16x8*)&Vtile[cur ^ 1][srow * 64 + sd] = gV;
      *(s16x8*)&Rw[rd0] = gR0;
      *(s16x8*)&Rw[rd1] = gR1;
    }
    __syncthreads();
  }

  // epilogue: stage 16 rows x 64 cols in wave-private aw, then coalesced
  // 16B/lane stores (each instr: 8 rows x 128B contiguous).
#pragma unroll
  for (int n = 0; n < 4; ++n)
#pragma unroll
    for (int j = 0; j < 4; ++j)
      aw[(g * 4 + j) * 64 + n * 16 + q] = f2bf(acc[n][j]);
  ushort* P = Ctx + ((size_t)(b * SS) + qblk + w * 16) * DD + h * 64;
#pragma unroll
  for (int it = 0; it < 2; ++it) {
    const int idx = it * 64 + lane;
    const int row = idx >> 3;
    const int seg = idx & 7;
    s16x8 v = *(const s16x8*)&aw[row * 64 + seg * 8];
    *(s16x8*)(P + (size_t)row * DD + seg * 8) = v;
  }
}

extern "C" void kernel_launch(void* const* d_in, const int* in_sizes, int n_in,
                              void* d_out, int out_size, void* d_ws, size_t ws_size,
                              hipStream_t stream) {
  const float* Query = (const float*)d_in[0];
  const float* Key   = (const float*)d_in[1];
  const float* Value = (const float*)d_in[2];
  const float* Wq    = (const float*)d_in[3];
  const float* Wk    = (const float*)d_in[4];
  const float* Wv    = (const float*)d_in[5];
  const float* Wo    = (const float*)d_in[6];

  size_t off = 0;
  char* ws = (char*)d_ws;
  auto alloc = [&](size_t bytes) -> void* {
    void* p = ws + off;
    off += (bytes + 255) & ~(size_t)255;
    return p;
  };
  const size_t nX = (size_t)MM * DD;       // 4194304
  const size_t nW = (size_t)DD * DD;       // 1048576
  const size_t nS = (size_t)BB * SS * SS;  // 8388608
  ushort* Wqb  = (ushort*)alloc(nW * 2);
  ushort* Wkb  = (ushort*)alloc(nW * 2);
  ushort* Wvb  = (ushort*)alloc(nW * 2);
  ushort* Wob  = (ushort*)alloc(nW * 2);
  ushort* Qp   = (ushort*)alloc(nX * 2);
  ushort* Kp   = (ushort*)alloc(nX * 2);
  ushort* Vtb  = (ushort*)alloc(nX * 2);
  ushort* Rden = (ushort*)alloc(nS * 2);   // bf16 1/den, 16.7 MB
  ushort* Ctx  = (ushort*)alloc(nX * 2);

  // weights -> bf16: one launch for all four (saves 3 launch gaps)
  cvt4_kernel<<<dim3((int)(nW / 2048), 4), 256, 0, stream>>>(
      Wq, Wk, Wv, Wo, Wqb, Wkb, Wvb, Wob, (int)nW);

  // fused Q/K/V projections: 768 blocks = 3 blocks/CU
  qkv_proj<<<dim3(32, 8, 3), 256, 0, stream>>>(
      Query, Key, Value, Wqb, Wkb, Wvb, Qp, Kp, Vtb);

  den_kernel<<<dim3(16, 16, 2), 256, 0, stream>>>(Qp, Kp, Rden);
  attn5_kernel<<<512, 512, 0, stream>>>(Qp, Kp, Vtb, Rden, Ctx);

  o_proj<<<dim3(32, 8), 256, 0, stream>>>(Ctx, Wob, (float*)d_out);
}

// Round 24
// 143.539 us; speedup vs baseline: 1.1341x; 1.0285x over previous
//
#include <hip/hip_runtime.h>
#include <stdint.h>

#define BB   2
#define SS   2048
#define DD   1024
#define HH   16
#define DKK  64
#define MM   (BB*SS)   // 4096 rows total

typedef __attribute__((ext_vector_type(4))) float f32x4;
typedef __attribute__((ext_vector_type(8))) short s16x8;

union RdU { ushort u[8]; s16x8 v; };

#define MFMA_B16(a, b, c) __builtin_amdgcn_mfma_f32_16x16x32_bf16((a), (b), (c), 0, 0, 0)

__device__ __forceinline__ ushort f2bf(float f) {
  uint u = __float_as_uint(f);
  u += 0x7FFFu + ((u >> 16) & 1u);   // round-to-nearest-even
  return (ushort)(u >> 16);
}
__device__ __forceinline__ float bf2f(ushort u) {
  return __uint_as_float((uint)u << 16);
}
// 2^x: __builtin_amdgcn_exp2f lowers to a bare v_exp_f32 (R17: 76->61us vs
// libm exp2f; R14's inline-asm broke TRANS hazards).  Scores pre-scaled log2(e).
#if __has_builtin(__builtin_amdgcn_exp2f)
#define EXP2(x) __builtin_amdgcn_exp2f(x)
#else
#define EXP2(x) exp2f(x)
#endif

// 8x fp32 (in regs) -> bf16 via packed cvt (RNE, proven R12)
__device__ __forceinline__ s16x8 pack8(float4 a, float4 b) {
  union { uint u[4]; s16x8 v; } r;
  asm("v_cvt_pk_bf16_f32 %0, %1, %2" : "=v"(r.u[0]) : "v"(a.x), "v"(a.y));
  asm("v_cvt_pk_bf16_f32 %0, %1, %2" : "=v"(r.u[1]) : "v"(a.z), "v"(a.w));
  asm("v_cvt_pk_bf16_f32 %0, %1, %2" : "=v"(r.u[2]) : "v"(b.x), "v"(b.y));
  asm("v_cvt_pk_bf16_f32 %0, %1, %2" : "=v"(r.u[3]) : "v"(b.z), "v"(b.w));
  return r.v;
}
__device__ __forceinline__ s16x8 cvt8(const float* src) {
  return pack8(*(const float4*)src, *(const float4*)(src + 4));
}

// Q pre-scale folds 1/sqrt(DK) AND log2(e).
#define QSCALE (0.125f * 1.4426950408889634f)

// ---------------- fp32 -> bf16 convert: all 4 weights in ONE launch ----------------
__global__ void cvt4_kernel(const float* __restrict__ s0, const float* __restrict__ s1,
                            const float* __restrict__ s2, const float* __restrict__ s3,
                            ushort* __restrict__ d0, ushort* __restrict__ d1,
                            ushort* __restrict__ d2, ushort* __restrict__ d3, int n) {
  const int w = blockIdx.y;
  const float*  src = (w == 0) ? s0 : (w == 1) ? s1 : (w == 2) ? s2 : s3;
  ushort*       dst = (w == 0) ? d0 : (w == 1) ? d1 : (w == 2) ? d2 : d3;
  int i = (blockIdx.x * 256 + threadIdx.x) * 8;
  if (i >= n) return;
  *(s16x8*)(dst + i) = cvt8(src + i);
}

// ---------------- fused Q/K/V projection: z selects proj ----------------
// R20: distance-2 pipeline (loads for step s+2 issue at step s; full step of
// HBM latency cover; proven 162.8->154.8us).
__global__ __launch_bounds__(256, 2) void qkv_proj(
    const float* __restrict__ Ia, const float* __restrict__ Ib, const float* __restrict__ Ic,
    const ushort* __restrict__ Wa, const ushort* __restrict__ Wb, const ushort* __restrict__ Wc,
    ushort* __restrict__ Oa, ushort* __restrict__ Ob, ushort* __restrict__ Oc)
{
  __shared__ ushort As[2][128 * 32];   // 16 KB
  __shared__ ushort Bs[2][128 * 32];   // 16 KB
  const int tid  = threadIdx.x;
  const int lane = tid & 63, wave = tid >> 6;
  const int q = lane & 15, g = lane >> 4;
  const int wr = wave >> 1, wc = wave & 1;
  const int mblk = blockIdx.x * 128, nblk = blockIdx.y * 128;
  const int mode = blockIdx.z;

  const float*  A = (mode == 0) ? Ia : (mode == 1) ? Ib : Ic;
  const ushort* W = (mode == 0) ? Wa : (mode == 1) ? Wb : Wc;

  f32x4 acc[4][4];
  {
    f32x4 z = {0.f, 0.f, 0.f, 0.f};
#pragma unroll
    for (int i = 0; i < 4; ++i)
#pragma unroll
      for (int j = 0; j < 4; ++j) acc[i][j] = z;
  }

  const int r0 = tid >> 2;            // staging row
  const int e0 = (tid & 3) * 8;       // staging element offset within row
  const size_t arow0 = (size_t)(mblk + r0) * 1024 + e0;
  const size_t arow1 = (size_t)(mblk + r0 + 64) * 1024 + e0;
  const size_t wrow0 = (size_t)(nblk + r0) * 1024 + e0;
  const size_t wrow1 = (size_t)(nblk + r0 + 64) * 1024 + e0;

  // prologue: stage step 0 direct; load step 1 into regs
#pragma unroll
  for (int it = 0; it < 2; ++it) {
    const int row = r0 + it * 64;
    *(s16x8*)&As[0][row * 32 + e0] = cvt8(A + (it ? arow1 : arow0));
    *(s16x8*)&Bs[0][row * 32 + e0] = *(const s16x8*)(W + (it ? wrow1 : wrow0));
  }
  float4 fa0_0, fa0_1, fa1_0, fa1_1;
  s16x8  wg0, wg1;
  {
    const float* p0 = A + arow0 + 32;
    const float* p1 = A + arow1 + 32;
    fa0_0 = *(const float4*)p0;  fa0_1 = *(const float4*)(p0 + 4);
    fa1_0 = *(const float4*)p1;  fa1_1 = *(const float4*)(p1 + 4);
    wg0 = *(const s16x8*)(W + wrow0 + 32);
    wg1 = *(const s16x8*)(W + wrow1 + 32);
  }
  __syncthreads();

  for (int s = 0; s < 32; ++s) {
    const int cur = s & 1;
    // issue step s+2 loads
    float4 na0_0, na0_1, na1_0, na1_1;
    s16x8  nw0, nw1;
    if (s < 30) {
      const int k0 = (s + 2) * 32;
      const float* p0 = A + arow0 + k0;
      const float* p1 = A + arow1 + k0;
      na0_0 = *(const float4*)p0;  na0_1 = *(const float4*)(p0 + 4);
      na1_0 = *(const float4*)p1;  na1_1 = *(const float4*)(p1 + 4);
      nw0 = *(const s16x8*)(W + wrow0 + k0);
      nw1 = *(const s16x8*)(W + wrow1 + k0);
    }
    // compute step s from buf[cur]
    s16x8 af[4], bf[4];
#pragma unroll
    for (int t = 0; t < 4; ++t) {
      af[t] = *(const s16x8*)&As[cur][(wr * 64 + t * 16 + q) * 32 + g * 8];
      bf[t] = *(const s16x8*)&Bs[cur][(wc * 64 + t * 16 + q) * 32 + g * 8];
    }
#pragma unroll
    for (int mt = 0; mt < 4; ++mt)
#pragma unroll
      for (int nt = 0; nt < 4; ++nt)
        acc[mt][nt] = MFMA_B16(af[mt], bf[nt], acc[mt][nt]);
    // write step s+1 regs into the other buffer
    if (s < 31) {
      *(s16x8*)&As[cur ^ 1][r0 * 32 + e0]        = pack8(fa0_0, fa0_1);
      *(s16x8*)&As[cur ^ 1][(r0 + 64) * 32 + e0] = pack8(fa1_0, fa1_1);
      *(s16x8*)&Bs[cur ^ 1][r0 * 32 + e0]        = wg0;
      *(s16x8*)&Bs[cur ^ 1][(r0 + 64) * 32 + e0] = wg1;
    }
    // rotate
    if (s < 30) {
      fa0_0 = na0_0; fa0_1 = na0_1; fa1_0 = na1_0; fa1_1 = na1_1;
      wg0 = nw0; wg1 = nw1;
    }
    __syncthreads();
  }

  // epilogue (C layout: col = lane&15 (N), row = (lane>>4)*4 + j (M))
  if (mode == 2) {
    ushort* Vt = Oc;
#pragma unroll
    for (int mt = 0; mt < 4; ++mt)
#pragma unroll
      for (int nt = 0; nt < 4; ++nt) {
        const int s0 = mblk + wr * 64 + mt * 16 + g * 4;
        const int o  = nblk + wc * 64 + nt * 16 + q;
        const int h = o >> 6, dk = o & 63;
        const int b = s0 >> 11, sr = s0 & 2047;
        ushort4 pk;
        pk.x = f2bf(acc[mt][nt][0]); pk.y = f2bf(acc[mt][nt][1]);
        pk.z = f2bf(acc[mt][nt][2]); pk.w = f2bf(acc[mt][nt][3]);
        *(ushort4*)(Vt + ((size_t)((b * 16 + h) * 64 + dk)) * SS + sr) = pk;
      }
  } else {
    const float scale = (mode == 0) ? QSCALE : 1.0f;
    ushort* P = (mode == 0) ? Oa : Ob;
    ushort* wl = &As[0][wave * 1024];   // 2KB wave-private staging (reuse As)
    const int h0 = (nblk + wc * 64) >> 6;
#pragma unroll
    for (int mt = 0; mt < 4; ++mt) {
      const int s0 = mblk + wr * 64 + mt * 16;
      const int b  = s0 >> 11, sr0 = s0 & 2047;
#pragma unroll
      for (int nt = 0; nt < 4; ++nt)
#pragma unroll
        for (int j = 0; j < 4; ++j)
          wl[(g * 4 + j) * 64 + nt * 16 + q] = f2bf(acc[mt][nt][j] * scale);
      // same-wave LDS write->read: compiler inserts lgkmcnt wait
#pragma unroll
      for (int it = 0; it < 2; ++it) {
        s16x8 v = *(const s16x8*)((char*)wl + it * 1024 + lane * 16);
        const int lr = it * 8 + (lane >> 3);
        const int c  = (lane & 7) * 8;
        *(s16x8*)(P + ((size_t)((b * 16 + h0) * SS) + sr0 + lr) * DKK + c) = v;
      }
    }
  }
}

// ---------------- O-projection: Y = Ctx @ Wo^T -> fp32 d_out ----------------
__global__ __launch_bounds__(256, 2) void o_proj(
    const ushort* __restrict__ A, const ushort* __restrict__ W,
    float* __restrict__ O)
{
  __shared__ ushort As[2][128 * 32];
  __shared__ ushort Bs[2][128 * 32];
  const int tid  = threadIdx.x;
  const int lane = tid & 63, wave = tid >> 6;
  const int q = lane & 15, g = lane >> 4;
  const int wr = wave >> 1, wc = wave & 1;
  const int mblk = blockIdx.x * 128, nblk = blockIdx.y * 128;

  f32x4 acc[4][4];
  {
    f32x4 z = {0.f, 0.f, 0.f, 0.f};
#pragma unroll
    for (int i = 0; i < 4; ++i)
#pragma unroll
      for (int j = 0; j < 4; ++j) acc[i][j] = z;
  }

  const int r0 = tid >> 2;
  const int e0 = (tid & 3) * 8;
  const size_t arow0 = (size_t)(mblk + r0) * 1024 + e0;
  const size_t arow1 = (size_t)(mblk + r0 + 64) * 1024 + e0;
  const size_t wrow0 = (size_t)(nblk + r0) * 1024 + e0;
  const size_t wrow1 = (size_t)(nblk + r0 + 64) * 1024 + e0;

  // prologue: stage step 0 direct; load step 1 into regs
#pragma unroll
  for (int it = 0; it < 2; ++it) {
    const int row = r0 + it * 64;
    *(s16x8*)&As[0][row * 32 + e0] = *(const s16x8*)(A + (it ? arow1 : arow0));
    *(s16x8*)&Bs[0][row * 32 + e0] = *(const s16x8*)(W + (it ? wrow1 : wrow0));
  }
  s16x8 ag0, ag1, wg0, wg1;
  {
    ag0 = *(const s16x8*)(A + arow0 + 32);
    ag1 = *(const s16x8*)(A + arow1 + 32);
    wg0 = *(const s16x8*)(W + wrow0 + 32);
    wg1 = *(const s16x8*)(W + wrow1 + 32);
  }
  __syncthreads();

  for (int s = 0; s < 32; ++s) {
    const int cur = s & 1;
    s16x8 na0, na1, nw0, nw1;
    if (s < 30) {
      const int k0 = (s + 2) * 32;
      na0 = *(const s16x8*)(A + arow0 + k0);
      na1 = *(const s16x8*)(A + arow1 + k0);
      nw0 = *(const s16x8*)(W + wrow0 + k0);
      nw1 = *(const s16x8*)(W + wrow1 + k0);
    }
    s16x8 af[4], bf[4];
#pragma unroll
    for (int t = 0; t < 4; ++t) {
      af[t] = *(const s16x8*)&As[cur][(wr * 64 + t * 16 + q) * 32 + g * 8];
      bf[t] = *(const s16x8*)&Bs[cur][(wc * 64 + t * 16 + q) * 32 + g * 8];
    }
#pragma unroll
    for (int mt = 0; mt < 4; ++mt)
#pragma unroll
      for (int nt = 0; nt < 4; ++nt)
        acc[mt][nt] = MFMA_B16(af[mt], bf[nt], acc[mt][nt]);
    if (s < 31) {
      *(s16x8*)&As[cur ^ 1][r0 * 32 + e0]        = ag0;
      *(s16x8*)&As[cur ^ 1][(r0 + 64) * 32 + e0] = ag1;
      *(s16x8*)&Bs[cur ^ 1][r0 * 32 + e0]        = wg0;
      *(s16x8*)&Bs[cur ^ 1][(r0 + 64) * 32 + e0] = wg1;
    }
    if (s < 30) { ag0 = na0; ag1 = na1; wg0 = nw0; wg1 = nw1; }
    __syncthreads();
  }

#pragma unroll
  for (int mt = 0; mt < 4; ++mt)
#pragma unroll
    for (int nt = 0; nt < 4; ++nt)
#pragma unroll
      for (int j = 0; j < 4; ++j) {
        const int s = mblk + wr * 64 + mt * 16 + g * 4 + j;
        const int o = nblk + wc * 64 + nt * 16 + q;
        O[(size_t)s * DD + o] = acc[mt][nt][j];
      }
}

// ---------------- pass 1: rden = 1/sum_h exp(s) — 64-wide steps, double-buffered ----------------
// R23 epilogue: write Rden2 directly in attn's per-lane consumption order
// (tile = (b*16+qt)*32 + kt, 16KB each; ushort off = tid_t*16 + mt*4 + r
// where tid_t = (wc*4+nt)*64 + g*16 + q, kt = 2*blockIdx.x + wr).  Replaces
// the LDS-bounce transpose; attn then needs NO rden re-layout at all.
__global__ __launch_bounds__(256, 2) void den_kernel(
    const ushort* __restrict__ Qp, const ushort* __restrict__ Kp,
    ushort* __restrict__ Rden)
{
  __shared__ ushort smem[2][16384];     // [buf][As 8192 | Bs 8192] = 64 KB
  const int tid  = threadIdx.x;
  const int lane = tid & 63, wave = tid >> 6;
  const int q = lane & 15, g = lane >> 4;
  const int wr = wave >> 1, wc = wave & 1;
  const int kblk = blockIdx.x * 128, qblk = blockIdx.y * 128;
  const int b = blockIdx.z;

  f32x4 den[4][4];
  {
    f32x4 z = {0.f, 0.f, 0.f, 0.f};
#pragma unroll
    for (int i = 0; i < 4; ++i)
#pragma unroll
      for (int j = 0; j < 4; ++j) den[i][j] = z;
  }

  const int srow = tid >> 3, sseg = tid & 7;
  const int sd   = (sseg * 8) ^ ((srow & 7) << 3);

  const ushort* Kb0 = Kp + ((size_t)(b * 16) * SS + kblk) * DKK;
  const ushort* Qb0 = Qp + ((size_t)(b * 16) * SS + qblk) * DKK;

  // prologue: stage head 0 into buf 0
#pragma unroll
  for (int i = 0; i < 4; ++i) {
    const int row = srow + i * 32;
    *(s16x8*)&smem[0][row * 64 + sd]        = *(const s16x8*)(Kb0 + (size_t)row * DKK + sseg * 8);
    *(s16x8*)&smem[0][8192 + row * 64 + sd] = *(const s16x8*)(Qb0 + (size_t)row * DKK + sseg * 8);
  }
  __syncthreads();

  for (int s = 0; s < 16; ++s) {
    const int cur = s & 1;
    s16x8 nA[4], nB[4];
    if (s < 15) {
      const ushort* Kh = Kb0 + (size_t)(s + 1) * SS * DKK;
      const ushort* Qh = Qb0 + (size_t)(s + 1) * SS * DKK;
#pragma unroll
      for (int i = 0; i < 4; ++i) {
        const int row = srow + i * 32;
        nA[i] = *(const s16x8*)(Kh + (size_t)row * DKK + sseg * 8);
        nB[i] = *(const s16x8*)(Qh + (size_t)row * DKK + sseg * 8);
      }
    }
    s16x8 af[4][2], bf[4][2];
#pragma unroll
    for (int t = 0; t < 4; ++t) {
      const int ra = wr * 64 + t * 16 + q;
      const int rb = wc * 64 + t * 16 + q;
      af[t][0] = *(const s16x8*)&smem[cur][ra * 64 + ((g * 8) ^ ((ra & 7) << 3))];
      af[t][1] = *(const s16x8*)&smem[cur][ra * 64 + ((32 + g * 8) ^ ((ra & 7) << 3))];
      bf[t][0] = *(const s16x8*)&smem[cur][8192 + rb * 64 + ((g * 8) ^ ((rb & 7) << 3))];
      bf[t][1] = *(const s16x8*)&smem[cur][8192 + rb * 64 + ((32 + g * 8) ^ ((rb & 7) << 3))];
    }
#pragma unroll
    for (int mt = 0; mt < 4; ++mt)
#pragma unroll
      for (int nt = 0; nt < 4; ++nt) {
        f32x4 c = {0.f, 0.f, 0.f, 0.f};
        c = MFMA_B16(af[mt][0], bf[nt][0], c);
        c = MFMA_B16(af[mt][1], bf[nt][1], c);
#pragma unroll
        for (int r = 0; r < 4; ++r)
          den[mt][nt][r] += EXP2(c[r]);
      }
    if (s < 15) {
#pragma unroll
      for (int i = 0; i < 4; ++i) {
        const int row = srow + i * 32;
        *(s16x8*)&smem[cur ^ 1][row * 64 + sd]        = nA[i];
        *(s16x8*)&smem[cur ^ 1][8192 + row * 64 + sd] = nB[i];
      }
    }
    __syncthreads();
  }

  // epilogue: direct Rden2 stores (attn per-lane order; derivation in header)
  ushort* R2 = Rden + (((size_t)(b * 16 + blockIdx.y) * 32) + (blockIdx.x * 2 + wr)) * 8192;
#pragma unroll
  for (int nt = 0; nt < 4; ++nt) {
    const int tid_t = (wc * 4 + nt) * 64 + g * 16 + q;
#pragma unroll
    for (int mt = 0; mt < 4; ++mt) {
      const float i0 = 1.0f / den[mt][nt][0], i1 = 1.0f / den[mt][nt][1];
      const float i2 = 1.0f / den[mt][nt][2], i3 = 1.0f / den[mt][nt][3];
      union { ushort4 s; uint2 u; } pk;
      asm("v_cvt_pk_bf16_f32 %0, %1, %2" : "=v"(pk.u.x) : "v"(i0), "v"(i1));
      asm("v_cvt_pk_bf16_f32 %0, %1, %2" : "=v"(pk.u.y) : "v"(i2), "v"(i3));
      *(ushort4*)(R2 + tid_t * 16 + mt * 4) = pk.s;
    }
  }
}

// ---------------- pass 2: block-tiled attention, double-buffered K/V ----------------
// R23: rden read directly from Rden2 into registers (32B/lane contiguous,
// wave covers 2KB linear — perfectly coalesced), distance-1 prefetched like
// K/V.  Rw staging + swizzle deleted; LDS 64->48 KB.
__global__ __launch_bounds__(512, 2) void attn5_kernel(
    const ushort* __restrict__ Qp, const ushort* __restrict__ Kp,
    const ushort* __restrict__ Vt, const ushort* __restrict__ Rden,
    ushort* __restrict__ Ctx)
{
  __shared__ ushort Ktile[2][64 * 64];   // 16 KB, row k (swz by k&7)
  __shared__ ushort Vtile[2][64 * 64];   // 16 KB, row dk (swz by dk&7)
  __shared__ ushort aw_all[8][16 * 64];  // 16 KB, per-wave P / epilogue

  const int tid  = threadIdx.x;
  const int lane = tid & 63;
  const int w    = tid >> 6;             // wave 0..7
  const int q    = lane & 15;
  const int g    = lane >> 4;
  const int bid  = blockIdx.x;
  const int bh   = bid & 31;
  const int b    = bh >> 4, h = bh & 15;
  const int qt   = bid >> 5;             // 0..15
  const int qblk = qt * 128;

  const ushort* Qb = Qp + ((size_t)bh * SS + qblk + w * 16 + q) * DKK + g * 8;
  s16x8 qf0 = *(const s16x8*)(Qb);
  s16x8 qf1 = *(const s16x8*)(Qb + 32);

  const ushort* Ks = Kp + (size_t)bh * SS * DKK;
  const ushort* Vs = Vt + (size_t)bh * DKK * SS;
  const ushort* Rs = Rden + ((size_t)(b * 16 + qt) * 32) * 8192 + tid * 16;

  f32x4 acc[4];
  {
    f32x4 z = {0.f, 0.f, 0.f, 0.f};
#pragma unroll
    for (int n = 0; n < 4; ++n) acc[n] = z;
  }

  ushort* aw = aw_all[w];
  const int srow = tid >> 3, sseg = tid & 7;
  const int sd   = (sseg * 8) ^ ((srow & 7) << 3);

  // prologue: stage phase 0 into buffer 0; rden phase 0 into regs
  RdU rdA, rdB;
  {
    s16x8 gK  = *(const s16x8*)(Ks + tid * 8);
    s16x8 gV  = *(const s16x8*)(Vs + (size_t)srow * SS + sseg * 8);
    rdA.v = *(const s16x8*)(Rs);
    rdB.v = *(const s16x8*)(Rs + 8);
    *(s16x8*)&Ktile[0][srow * 64 + sd] = gK;
    *(s16x8*)&Vtile[0][srow * 64 + sd] = gV;
  }
  __syncthreads();

  for (int kt = 0; kt < 32; ++kt) {
    const int cur = kt & 1;
    // ---- issue next tile's global loads (latency hides under compute)
    s16x8 gK, gV;
    RdU nrA, nrB;
    if (kt < 31) {
      const int k1 = (kt + 1) * 64;
      gK  = *(const s16x8*)(Ks + (size_t)k1 * DKK + tid * 8);
      gV  = *(const s16x8*)(Vs + (size_t)srow * SS + k1 + sseg * 8);
      nrA.v = *(const s16x8*)(Rs + (size_t)(kt + 1) * 8192);
      nrB.v = *(const s16x8*)(Rs + (size_t)(kt + 1) * 8192 + 8);
    }
    const ushort* Kt = Ktile[cur];
    const ushort* Vv = Vtile[cur];

    // ---- QK scores -> exp2 * rden -> P into wave-private aw
#pragma unroll
    for (int ks = 0; ks < 4; ++ks) {
      const int kr = ks * 16 + q;
      s16x8 a0 = *(const s16x8*)&Kt[kr * 64 + ((g * 8) ^ ((kr & 7) << 3))];
      s16x8 a1 = *(const s16x8*)&Kt[kr * 64 + ((32 + g * 8) ^ ((kr & 7) << 3))];
      f32x4 c = {0.f, 0.f, 0.f, 0.f};
      c = MFMA_B16(a0, qf0, c);
      c = MFMA_B16(a1, qf1, c);
      const ushort* ru = (ks < 2) ? rdA.u : rdB.u;
      const int o4 = (ks & 1) * 4;
      float p0 = EXP2(c[0]) * bf2f(ru[o4 + 0]);
      float p1 = EXP2(c[1]) * bf2f(ru[o4 + 1]);
      float p2 = EXP2(c[2]) * bf2f(ru[o4 + 2]);
      float p3 = EXP2(c[3]) * bf2f(ru[o4 + 3]);
      uint2 pp;
      asm("v_cvt_pk_bf16_f32 %0, %1, %2" : "=v"(pp.x) : "v"(p0), "v"(p1));
      asm("v_cvt_pk_bf16_f32 %0, %1, %2" : "=v"(pp.y) : "v"(p2), "v"(p3));
      *(uint2*)&aw[q * 64 + ((ks * 16 + g * 4) ^ ((q & 7) << 3))] = pp;
    }
    // ---- PV over the 64-key tile (same-wave aw; lgkmcnt auto)
#pragma unroll
    for (int kc = 0; kc < 2; ++kc) {
      s16x8 vf[4];
#pragma unroll
      for (int n = 0; n < 4; ++n) {
        const int vr = n * 16 + q;
        vf[n] = *(const s16x8*)&Vv[vr * 64 + ((kc * 32 + g * 8) ^ ((vr & 7) << 3))];
      }
      s16x8 pa = *(const s16x8*)&aw[q * 64 + ((kc * 32 + g * 8) ^ ((q & 7) << 3))];
#pragma unroll
      for (int n = 0; n < 4; ++n)
        acc[n] = MFMA_B16(pa, vf[n], acc[n]);
    }
    // ---- write staged regs into the other buffer; rotate rden regs
    if (kt < 31) {
      *(s16x8*)&Ktile[cur ^ 1][srow * 64 + sd] = gK;
      *(s16x8*)&Vtile[cur ^ 1][srow * 64 + sd] = gV;
      rdA = nrA; rdB = nrB;
    }
    __syncthreads();
  }

  // epilogue: stage 16 rows x 64 cols in wave-private aw, then coalesced
  // 16B/lane stores (each instr: 8 rows x 128B contiguous).
#pragma unroll
  for (int n = 0; n < 4; ++n)
#pragma unroll
    for (int j = 0; j < 4; ++j)
      aw[(g * 4 + j) * 64 + n * 16 + q] = f2bf(acc[n][j]);
  ushort* P = Ctx + ((size_t)(b * SS) + qblk + w * 16) * DD + h * 64;
#pragma unroll
  for (int it = 0; it < 2; ++it) {
    const int idx = it * 64 + lane;
    const int row = idx >> 3;
    const int seg = idx & 7;
    s16x8 v = *(const s16x8*)&aw[row * 64 + seg * 8];
    *(s16x8*)(P + (size_t)row * DD + seg * 8) = v;
  }
}

extern "C" void kernel_launch(void* const* d_in, const int* in_sizes, int n_in,
                              void* d_out, int out_size, void* d_ws, size_t ws_size,
                              hipStream_t stream) {
  const float* Query = (const float*)d_in[0];
  const float* Key   = (const float*)d_in[1];
  const float* Value = (const float*)d_in[2];
  const float* Wq    = (const float*)d_in[3];
  const float* Wk    = (const float*)d_in[4];
  const float* Wv    = (const float*)d_in[5];
  const float* Wo    = (const float*)d_in[6];

  size_t off = 0;
  char* ws = (char*)d_ws;
  auto alloc = [&](size_t bytes) -> void* {
    void* p = ws + off;
    off += (bytes + 255) & ~(size_t)255;
    return p;
  };
  const size_t nX = (size_t)MM * DD;       // 4194304
  const size_t nW = (size_t)DD * DD;       // 1048576
  const size_t nS = (size_t)BB * SS * SS;  // 8388608
  ushort* Wqb  = (ushort*)alloc(nW * 2);
  ushort* Wkb  = (ushort*)alloc(nW * 2);
  ushort* Wvb  = (ushort*)alloc(nW * 2);
  ushort* Wob  = (ushort*)alloc(nW * 2);
  ushort* Qp   = (ushort*)alloc(nX * 2);
  ushort* Kp   = (ushort*)alloc(nX * 2);
  ushort* Vtb  = (ushort*)alloc(nX * 2);
  ushort* Rden = (ushort*)alloc(nS * 2);   // bf16 1/den (Rden2 layout), 16.7 MB
  ushort* Ctx  = (ushort*)alloc(nX * 2);

  // weights -> bf16: one launch for all four
  cvt4_kernel<<<dim3((int)(nW / 2048), 4), 256, 0, stream>>>(
      Wq, Wk, Wv, Wo, Wqb, Wkb, Wvb, Wob, (int)nW);

  // fused Q/K/V projections: 768 blocks = 3 blocks/CU
  qkv_proj<<<dim3(32, 8, 3), 256, 0, stream>>>(
      Query, Key, Value, Wqb, Wkb, Wvb, Qp, Kp, Vtb);

  den_kernel<<<dim3(16, 16, 2), 256, 0, stream>>>(Qp, Kp, Rden);
  attn5_kernel<<<512, 512, 0, stream>>>(Qp, Kp, Vtb, Rden, Ctx);

  o_proj<<<dim3(32, 8), 256, 0, stream>>>(Ctx, Wob, (float*)d_out);
}